// Round 12
// baseline (1078.518 us; speedup 1.0000x reference)
//
#include <hip/hip_runtime.h>
#include <hip/hip_bf16.h>

#define HD 128
#define TILE 64
#define ST 136  // LDS row stride in bf16 (272B; b128/b64 access -> 2-way bank alias, free)

typedef __attribute__((ext_vector_type(8))) short bf16x8;
typedef __attribute__((ext_vector_type(4))) float f32x4;

// fast GELU (A&S 7.1.26, |eps|<=1.5e-7). Safe only with the hi/lo tin pair (R8):
// the single-plane tin->bf16 quantizer amplified 1e-6 perturbations into 0.25
// absmax failures (R3/R4/R6).
__device__ __forceinline__ float gelu_f(float x) {
    float y = fabsf(x) * 0.70710678118654752f;
    float t = __builtin_amdgcn_rcpf(fmaf(0.3275911f, y, 1.0f));
    float p = t * fmaf(t, fmaf(t, fmaf(t, fmaf(t, 1.061405429f, -1.453152027f),
                                       1.421413741f), -0.284496736f), 0.254829592f);
    float E = fmaf(-p, __expf(-y * y), 1.0f);
    return 0.5f * x * (1.0f + copysignf(E, x));
}
__device__ __forceinline__ unsigned short f2bf(float f) {
    unsigned int x = __float_as_uint(f);
    x = x + 0x7fffu + ((x >> 16) & 1u);
    return (unsigned short)(x >> 16);
}
__device__ __forceinline__ unsigned int pk2bf(float lo, float hi) {
    return (unsigned int)f2bf(lo) | ((unsigned int)f2bf(hi) << 16);
}
__device__ __forceinline__ float bf2f(unsigned short u) {
    return __uint_as_float((unsigned int)u << 16);
}

// OPERAND-SWAPPED MFMA: D = Wt_frag (A-op) x X_frag (B-op).
// wt layout: wt[((n0*4+kk)*64+l)*8+e] = W[kk*32+(l>>4)*8+e][n0*16+(l&15)]
// Result: acc[n0][q] = u[node wrow+(l&15)][feature n0*16+(l>>4)*4+q]
// -> lane owns ONE node row; epilogues become contiguous 4-feature vectors.
__device__ __forceinline__ void mm_mfma(const unsigned short* sA, int wrow, int lane,
                                        const unsigned short* __restrict__ wt, f32x4 acc[8]) {
    int m = lane & 15, kb = lane >> 4;
    bf16x8 a[4];
#pragma unroll
    for (int kk = 0; kk < 4; ++kk)
        a[kk] = *(const bf16x8*)(sA + (wrow + m) * ST + kk * 32 + kb * 8);
#pragma unroll
    for (int n0 = 0; n0 < 8; ++n0) {
        f32x4 c = {0.f, 0.f, 0.f, 0.f};
#pragma unroll
        for (int kk = 0; kk < 4; ++kk) {
            bf16x8 b = *(const bf16x8*)(wt + ((size_t)((n0 * 4 + kk) * 64 + lane)) * 8);
            c = __builtin_amdgcn_mfma_f32_16x16x32_bf16(b, a[kk], c, 0, 0, 0);
        }
        acc[n0] = c;
    }
}

// two-plane (hi+lo): acc = W^T x (Hi + Lo), chained accumulation
__device__ __forceinline__ void mm_mfma2(const unsigned short* sH, const unsigned short* sL,
                                         int wrow, int lane,
                                         const unsigned short* __restrict__ wt, f32x4 acc[8]) {
    int m = lane & 15, kb = lane >> 4;
    bf16x8 ah[4], al[4];
#pragma unroll
    for (int kk = 0; kk < 4; ++kk) {
        ah[kk] = *(const bf16x8*)(sH + (wrow + m) * ST + kk * 32 + kb * 8);
        al[kk] = *(const bf16x8*)(sL + (wrow + m) * ST + kk * 32 + kb * 8);
    }
#pragma unroll
    for (int n0 = 0; n0 < 8; ++n0) {
        f32x4 c = {0.f, 0.f, 0.f, 0.f};
#pragma unroll
        for (int kk = 0; kk < 4; ++kk) {
            bf16x8 b = *(const bf16x8*)(wt + ((size_t)((n0 * 4 + kk) * 64 + lane)) * 8);
            c = __builtin_amdgcn_mfma_f32_16x16x32_bf16(b, ah[kk], c, 0, 0, 0);
            c = __builtin_amdgcn_mfma_f32_16x16x32_bf16(b, al[kk], c, 0, 0, 0);
        }
        acc[n0] = c;
    }
}

// bias + LN + GELU for the swapped C-layout: lane owns node wrow+m, 32 values
// u[n0][q] = feature n0*16+kb*4+q. Row-reduce = local sum + xor16/xor32.
__device__ __forceinline__ void bias_ln_gelu(f32x4 acc[8], float u[8][4],
                                             const float* bias, const float* g,
                                             const float* be, int kb) {
    float s = 0.f, ss = 0.f;
#pragma unroll
    for (int n0 = 0; n0 < 8; ++n0)
#pragma unroll
        for (int q = 0; q < 4; ++q) {
            float x = acc[n0][q] + bias[n0 * 16 + kb * 4 + q];
            u[n0][q] = x;
            s += x; ss += x * x;
        }
    s += __shfl_xor(s, 16); ss += __shfl_xor(ss, 16);
    s += __shfl_xor(s, 32); ss += __shfl_xor(ss, 32);
    float mean = s * (1.f / HD);
    float inv = rsqrtf(ss * (1.f / HD) - mean * mean + 1e-5f);
#pragma unroll
    for (int n0 = 0; n0 < 8; ++n0)
#pragma unroll
        for (int q = 0; q < 4; ++q) {
            int c = n0 * 16 + kb * 4 + q;
            u[n0][q] = gelu_f((u[n0][q] - mean) * inv * g[c] + be[c]);
        }
}

// ---------------- weight prep: bf16 + MFMA-fragment order (10 matrices 128x128)
__global__ void prep_weights(const float* __restrict__ ne_w2, const float* __restrict__ ee_w2,
                             const float* __restrict__ cv_w1, const float* __restrict__ cv_w2,
                             unsigned short* __restrict__ wbf) {
    int mat = blockIdx.x;
    const float* src = (mat == 0) ? ne_w2
                     : (mat == 1) ? ee_w2
                     : (mat < 6)  ? cv_w1 + (size_t)(mat - 2) * HD * HD
                                  : cv_w2 + (size_t)(mat - 6) * HD * HD;
    unsigned short* dst = wbf + (size_t)mat * HD * HD;
    for (int i = threadIdx.x; i < HD * HD; i += 256) {
        int e = i & 7, lane = (i >> 3) & 63, f = i >> 9;  // f = n0*4+kk
        int m = lane & 15, kb = lane >> 4;
        int n0 = f >> 2, kk = f & 3;
        int k = kk * 32 + kb * 8 + e;
        int c = n0 * 16 + m;
        dst[i] = f2bf(src[(size_t)k * HD + c]);
    }
}

// ---------------- encoder: Linear(IN_DIM->128)+LN+GELU, MFMA Linear(128->128)+LN+GELU
template <int IN_DIM, bool EDGE>
__global__ __launch_bounds__(256) void encoder_mfma(
    const float* __restrict__ in, const float* __restrict__ w1,
    const float* __restrict__ b1, const float* __restrict__ g1,
    const float* __restrict__ be1, const unsigned short* __restrict__ wt2,
    const float* __restrict__ b2, const float* __restrict__ g2,
    const float* __restrict__ be2, float* __restrict__ h_out,
    unsigned short* __restrict__ e_perm, const int* __restrict__ pos, int rows) {
    __shared__ __align__(16) unsigned short s_A[TILE * ST];
    __shared__ float s_vec[6][HD];
    __shared__ int s_pos[TILE];

    int tid = threadIdx.x;
    int row0 = blockIdx.x * TILE;
    if (tid < HD) {
        s_vec[0][tid] = b1[tid]; s_vec[1][tid] = g1[tid]; s_vec[2][tid] = be1[tid];
        s_vec[3][tid] = b2[tid]; s_vec[4][tid] = g2[tid]; s_vec[5][tid] = be2[tid];
    }
    if (EDGE && tid < TILE) {
        int gr = row0 + tid;
        s_pos[tid] = (gr < rows) ? pos[gr] : 0;
    }
    __syncthreads();

    // phase A: thread (tr,tc) owns rows r0..r0+3, cols c0..c0+7; w1 in registers
    int tr = tid >> 4, tc = tid & 15;
    int r0 = tr * 4, c0 = tc * 8;
    float w1r[IN_DIM][8];
#pragma unroll
    for (int k = 0; k < IN_DIM; ++k) {
        float4 pa = *(const float4*)(w1 + (size_t)k * HD + c0);
        float4 pb = *(const float4*)(w1 + (size_t)k * HD + c0 + 4);
        w1r[k][0] = pa.x; w1r[k][1] = pa.y; w1r[k][2] = pa.z; w1r[k][3] = pa.w;
        w1r[k][4] = pb.x; w1r[k][5] = pb.y; w1r[k][6] = pb.z; w1r[k][7] = pb.w;
    }
    float v[4][8];
#pragma unroll
    for (int i = 0; i < 4; ++i)
#pragma unroll
        for (int j = 0; j < 8; ++j) v[i][j] = s_vec[0][c0 + j];
#pragma unroll
    for (int i = 0; i < 4; ++i) {
        int gr = min(row0 + r0 + i, rows - 1);
        float xr[IN_DIM];
        if constexpr (IN_DIM == 4) {
            float4 t4 = *(const float4*)(in + (size_t)gr * 4);
            xr[0] = t4.x; xr[1] = t4.y; xr[2] = t4.z; xr[3] = t4.w;
        } else {
#pragma unroll
            for (int k = 0; k < IN_DIM; ++k) xr[k] = in[(size_t)gr * IN_DIM + k];
        }
#pragma unroll
        for (int k = 0; k < IN_DIM; ++k)
#pragma unroll
            for (int j = 0; j < 8; ++j) v[i][j] = fmaf(xr[k], w1r[k][j], v[i][j]);
    }
    // LN+GELU per row (16-lane tc groups), pack to LDS
#pragma unroll
    for (int i = 0; i < 4; ++i) {
        float s = 0.f, ss = 0.f;
#pragma unroll
        for (int j = 0; j < 8; ++j) { s += v[i][j]; ss += v[i][j] * v[i][j]; }
#pragma unroll
        for (int msk = 1; msk < 16; msk <<= 1) { s += __shfl_xor(s, msk); ss += __shfl_xor(ss, msk); }
        float mean = s * (1.f / HD);
        float inv = rsqrtf(ss * (1.f / HD) - mean * mean + 1e-5f);
#pragma unroll
        for (int j = 0; j < 8; ++j)
            v[i][j] = gelu_f((v[i][j] - mean) * inv * s_vec[1][c0 + j] + s_vec[2][c0 + j]);
        uint4 q4;
        q4.x = pk2bf(v[i][0], v[i][1]); q4.y = pk2bf(v[i][2], v[i][3]);
        q4.z = pk2bf(v[i][4], v[i][5]); q4.w = pk2bf(v[i][6], v[i][7]);
        *(uint4*)&s_A[(r0 + i) * ST + c0] = q4;
    }
    __syncthreads();

    // phase B: swapped MFMA -> lane owns node wrow+m, features n0*16+kb*4+q
    int wave = tid >> 6, lane = tid & 63;
    int m = lane & 15, kb = lane >> 4;
    int wrow = wave * 16;
    f32x4 acc[8];
    mm_mfma(s_A, wrow, lane, wt2, acc);
    float u[8][4];
    bias_ln_gelu(acc, u, s_vec[3], s_vec[4], s_vec[5], kb);

    if (EDGE) {
        __syncthreads();  // all B-frag LDS reads complete before overwrite
#pragma unroll
        for (int n0 = 0; n0 < 8; ++n0) {
            uint2 p;
            p.x = pk2bf(u[n0][0], u[n0][1]);
            p.y = pk2bf(u[n0][2], u[n0][3]);
            *(uint2*)&s_A[(wrow + m) * ST + n0 * 16 + kb * 4] = p;
        }
        __syncthreads();
#pragma unroll
        for (int i = 0; i < 4; ++i) {
            int c = tid + i * 256;  // 1024 chunks of 8 bf16
            int r = c >> 4, cc = (c & 15) * 8;
            int gr = row0 + r;
            if (gr < rows) {
                uint4 q4 = *(uint4*)&s_A[r * ST + cc];
                *(uint4*)(e_perm + (size_t)s_pos[r] * HD + cc) = q4;
            }
        }
    } else {
        int grow = row0 + wrow + m;
        if (grow < rows) {
#pragma unroll
            for (int n0 = 0; n0 < 8; ++n0)
                *(float4*)(h_out + (size_t)grow * HD + n0 * 16 + kb * 4) =
                    make_float4(u[n0][0], u[n0][1], u[n0][2], u[n0][3]);
        }
    }
}

// ---------------- FUSED GINE layer (ping-pong h: reads h_old only, writes h_new)
// t_in = h_old + sum relu(h_old[src]+e); u = block(t_in); h_new = h_old + gelu(ln(u, nm))
__global__ __launch_bounds__(256) void agg_conv_mfma(
    const float* __restrict__ h_old, float* __restrict__ h_new,
    const unsigned short* __restrict__ e,
    const int* __restrict__ offs, const int* __restrict__ esrc,
    const unsigned short* __restrict__ wt1, const float* __restrict__ b1,
    const float* __restrict__ g1, const float* __restrict__ be1,
    const unsigned short* __restrict__ wt2, const float* __restrict__ b2,
    const float* __restrict__ g2, const float* __restrict__ be2,
    const float* __restrict__ nmg, const float* __restrict__ nmb, int rows) {
    __shared__ __align__(16) unsigned short s_A[TILE * ST];
    __shared__ __align__(16) unsigned short s_L[TILE * ST];
    __shared__ float s_vec[8][HD];

    int tid = threadIdx.x;
    int row0 = blockIdx.x * TILE;
    if (tid < HD) {
        s_vec[0][tid] = b1[tid];  s_vec[1][tid] = g1[tid];  s_vec[2][tid] = be1[tid];
        s_vec[3][tid] = b2[tid];  s_vec[4][tid] = g2[tid];  s_vec[5][tid] = be2[tid];
        s_vec[6][tid] = nmg[tid]; s_vec[7][tid] = nmb[tid];
    }
    int wave = tid >> 6, lane = tid & 63;

    // ---- aggregate phase: wave handles 16 rows; reads ONLY h_old (race-free)
    for (int t = 0; t < 16; ++t) {
        int row = wave * 16 + t;
        int n = row0 + row;
        if (n < rows) {
            int beg = offs[n], end = offs[n + 1];
            float ax = 0.f, ay = 0.f;
            int i = beg;
            for (; i + 4 <= end; i += 4) {
                int s0 = esrc[i], s1 = esrc[i + 1], s2 = esrc[i + 2], s3 = esrc[i + 3];
                float2 h0 = *(const float2*)(h_old + (size_t)s0 * HD + 2 * lane);
                float2 h1 = *(const float2*)(h_old + (size_t)s1 * HD + 2 * lane);
                float2 h2 = *(const float2*)(h_old + (size_t)s2 * HD + 2 * lane);
                float2 h3 = *(const float2*)(h_old + (size_t)s3 * HD + 2 * lane);
                unsigned int e0 = *(const unsigned int*)(e + (size_t)(i + 0) * HD + 2 * lane);
                unsigned int e1 = *(const unsigned int*)(e + (size_t)(i + 1) * HD + 2 * lane);
                unsigned int e2 = *(const unsigned int*)(e + (size_t)(i + 2) * HD + 2 * lane);
                unsigned int e3 = *(const unsigned int*)(e + (size_t)(i + 3) * HD + 2 * lane);
                ax += fmaxf(h0.x + __uint_as_float(e0 << 16), 0.f);
                ay += fmaxf(h0.y + __uint_as_float(e0 & 0xffff0000u), 0.f);
                ax += fmaxf(h1.x + __uint_as_float(e1 << 16), 0.f);
                ay += fmaxf(h1.y + __uint_as_float(e1 & 0xffff0000u), 0.f);
                ax += fmaxf(h2.x + __uint_as_float(e2 << 16), 0.f);
                ay += fmaxf(h2.y + __uint_as_float(e2 & 0xffff0000u), 0.f);
                ax += fmaxf(h3.x + __uint_as_float(e3 << 16), 0.f);
                ay += fmaxf(h3.y + __uint_as_float(e3 & 0xffff0000u), 0.f);
            }
            for (; i < end; ++i) {
                int src = esrc[i];
                float2 hv = *(const float2*)(h_old + (size_t)src * HD + 2 * lane);
                unsigned int ue = *(const unsigned int*)(e + (size_t)i * HD + 2 * lane);
                ax += fmaxf(hv.x + __uint_as_float(ue << 16), 0.f);
                ay += fmaxf(hv.y + __uint_as_float(ue & 0xffff0000u), 0.f);
            }
            float2 hn = *(const float2*)(h_old + (size_t)n * HD + 2 * lane);
            float tx = hn.x + ax, ty = hn.y + ay;
            unsigned short hx = f2bf(tx), hy = f2bf(ty);
            *(unsigned int*)&s_A[row * ST + 2 * lane] =
                (unsigned int)hx | ((unsigned int)hy << 16);
            *(unsigned int*)&s_L[row * ST + 2 * lane] =
                pk2bf(tx - bf2f(hx), ty - bf2f(hy));
        } else {
            *(unsigned int*)&s_A[row * ST + 2 * lane] = 0;
            *(unsigned int*)&s_L[row * ST + 2 * lane] = 0;
        }
    }
    __syncthreads();

    // ---- conv phase (arithmetic identical to R10)
    int m = lane & 15, kb = lane >> 4;
    int wrow = wave * 16;
    f32x4 acc[8];
    float u[8][4];

    mm_mfma2(s_A, s_L, wrow, lane, wt1, acc);
    bias_ln_gelu(acc, u, s_vec[0], s_vec[1], s_vec[2], kb);
    __syncthreads();  // all stage-1 LDS reads complete before t1 overwrite
#pragma unroll
    for (int n0 = 0; n0 < 8; ++n0) {
        uint2 p;
        p.x = pk2bf(u[n0][0], u[n0][1]);
        p.y = pk2bf(u[n0][2], u[n0][3]);
        *(uint2*)&s_A[(wrow + m) * ST + n0 * 16 + kb * 4] = p;
    }
    __syncthreads();

    mm_mfma(s_A, wrow, lane, wt2, acc);
    bias_ln_gelu(acc, u, s_vec[3], s_vec[4], s_vec[5], kb);
    // second LN (nm) + GELU, same layout
    {
        float s = 0.f, ss = 0.f;
#pragma unroll
        for (int n0 = 0; n0 < 8; ++n0)
#pragma unroll
            for (int q = 0; q < 4; ++q) { s += u[n0][q]; ss += u[n0][q] * u[n0][q]; }
        s += __shfl_xor(s, 16); ss += __shfl_xor(ss, 16);
        s += __shfl_xor(s, 32); ss += __shfl_xor(ss, 32);
        float mean = s * (1.f / HD);
        float inv = rsqrtf(ss * (1.f / HD) - mean * mean + 1e-5f);
#pragma unroll
        for (int n0 = 0; n0 < 8; ++n0)
#pragma unroll
            for (int q = 0; q < 4; ++q) {
                int c = n0 * 16 + kb * 4 + q;
                u[n0][q] = gelu_f((u[n0][q] - mean) * inv * s_vec[6][c] + s_vec[7][c]);
            }
    }
    int grow = row0 + wrow + m;
    if (grow < rows) {
#pragma unroll
        for (int n0 = 0; n0 < 8; ++n0) {
            size_t idx = (size_t)grow * HD + n0 * 16 + kb * 4;
            float4 hv = *(const float4*)(h_old + idx);
            hv.x += u[n0][0]; hv.y += u[n0][1]; hv.z += u[n0][2]; hv.w += u[n0][3];
            *(float4*)(h_new + idx) = hv;
        }
    }
}

// ---------------- CSR build ----------------
__global__ void zero_kernel(int* p, int n) {
    int i = blockIdx.x * 256 + threadIdx.x;
    if (i < n) p[i] = 0;
}
__global__ void hist_kernel(const int* __restrict__ dst, int* __restrict__ cnt, int n) {
    for (int i = blockIdx.x * 256 + threadIdx.x; i < n; i += gridDim.x * 256)
        atomicAdd(&cnt[dst[i]], 1);
}
__global__ __launch_bounds__(1024) void scan_block_kernel(
    const int* __restrict__ cnt, int* __restrict__ incl, int* __restrict__ bsum, int n) {
    __shared__ int buf[2][1024];
    int t = threadIdx.x;
    int i = blockIdx.x * 1024 + t;
    int v = (i < n) ? cnt[i] : 0;
    buf[0][t] = v;
    __syncthreads();
    int pin = 0;
    for (int off = 1; off < 1024; off <<= 1) {
        int x = buf[pin][t];
        if (t >= off) x += buf[pin][t - off];
        buf[pin ^ 1][t] = x;
        __syncthreads();
        pin ^= 1;
    }
    if (i < n) incl[i] = buf[pin][t];
    if (t == 1023) bsum[blockIdx.x] = buf[pin][t];
}
__global__ void scan_top_kernel(int* bsum, int nb) {
    int t = threadIdx.x;  // 64 threads
    int v = (t < nb) ? bsum[t] : 0;
    int orig = v;
#pragma unroll
    for (int off = 1; off < 64; off <<= 1) {
        int y = __shfl_up(v, off);
        if (t >= off) v += y;
    }
    if (t < nb) bsum[t] = v - orig;
}
__global__ void add_off_kernel(int* __restrict__ offs, const int* __restrict__ bsum,
                               int* __restrict__ cursor, int n) {
    int i = blockIdx.x * 256 + threadIdx.x;
    if (i == 0) { offs[0] = 0; cursor[0] = 0; }
    if (i < n) {
        int v = offs[i + 1] + bsum[i >> 10];
        offs[i + 1] = v;
        if (i + 1 < n) cursor[i + 1] = v;
    }
}
__global__ void scatter_kernel(const int* __restrict__ srcArr, const int* __restrict__ dstArr,
                               int* __restrict__ cursor, int* __restrict__ pos,
                               int* __restrict__ esrc, int n) {
    for (int i = blockIdx.x * 256 + threadIdx.x; i < n; i += gridDim.x * 256) {
        int d = dstArr[i];
        int p = atomicAdd(&cursor[d], 1);
        pos[i] = p;
        esrc[p] = srcArr[i];
    }
}

// ---------------- heads ----------------
__global__ __launch_bounds__(256) void head_kernel(
    const float* __restrict__ h, const float* __restrict__ dw1,
    const float* __restrict__ db1, const float* __restrict__ dg,
    const float* __restrict__ dbe, const float* __restrict__ dw2,
    const float* __restrict__ db2, const float* __restrict__ sw1,
    const float* __restrict__ sb1, const float* __restrict__ sg,
    const float* __restrict__ sbe, const float* __restrict__ sw2,
    const float* __restrict__ sb2, float* __restrict__ out, int nnodes) {
    __shared__ float s_wd[HD * 64];
    __shared__ float s_ws[HD * 64];
    __shared__ float s_vd[3][64];
    __shared__ float s_vs[3][64];
    __shared__ float s_w2d[64 * 3];
    __shared__ float s_w2s[64];
    __shared__ float s_h[4][HD];
    __shared__ float s_b2[4];

    int tid = threadIdx.x;
    for (int i = tid; i < HD * 64; i += 256) { s_wd[i] = dw1[i]; s_ws[i] = sw1[i]; }
    if (tid < 64) {
        s_vd[0][tid] = db1[tid]; s_vd[1][tid] = dg[tid]; s_vd[2][tid] = dbe[tid];
        s_vs[0][tid] = sb1[tid]; s_vs[1][tid] = sg[tid]; s_vs[2][tid] = sbe[tid];
        s_w2s[tid] = sw2[tid];
    }
    if (tid < 64 * 3) s_w2d[tid] = dw2[tid];
    if (tid == 0) { s_b2[0] = db2[0]; s_b2[1] = db2[1]; s_b2[2] = db2[2]; s_b2[3] = sb2[0]; }
    __syncthreads();

    int wave = tid >> 6, lane = tid & 63;
    float* disp = out;
    float* stress = out + (size_t)nnodes * 3;
    float* hout = out + (size_t)nnodes * 4;

    for (int n = blockIdx.x * 4 + wave; n < nnodes; n += gridDim.x * 4) {
        float2 hv = *(const float2*)(h + (size_t)n * HD + lane * 2);
        *(float2*)(hout + (size_t)n * HD + lane * 2) = hv;
        s_h[wave][lane * 2] = hv.x;
        s_h[wave][lane * 2 + 1] = hv.y;
        float accd = s_vd[0][lane], accs = s_vs[0][lane];
        for (int k = 0; k < HD; ++k) {
            float hx = s_h[wave][k];
            accd = fmaf(hx, s_wd[k * 64 + lane], accd);
            accs = fmaf(hx, s_ws[k * 64 + lane], accs);
        }
        float s = accd, ss = accd * accd;
#pragma unroll
        for (int msk = 1; msk < 64; msk <<= 1) { s += __shfl_xor(s, msk); ss += __shfl_xor(ss, msk); }
        float mean = s * (1.f / 64), inv = rsqrtf(ss * (1.f / 64) - mean * mean + 1e-5f);
        float d = gelu_f((accd - mean) * inv * s_vd[1][lane] + s_vd[2][lane]);
        s = accs; ss = accs * accs;
#pragma unroll
        for (int msk = 1; msk < 64; msk <<= 1) { s += __shfl_xor(s, msk); ss += __shfl_xor(ss, msk); }
        mean = s * (1.f / 64); inv = rsqrtf(ss * (1.f / 64) - mean * mean + 1e-5f);
        float sv = gelu_f((accs - mean) * inv * s_vs[1][lane] + s_vs[2][lane]);
        float p0 = d * s_w2d[lane * 3 + 0];
        float p1 = d * s_w2d[lane * 3 + 1];
        float p2 = d * s_w2d[lane * 3 + 2];
        float ps = sv * s_w2s[lane];
#pragma unroll
        for (int msk = 1; msk < 64; msk <<= 1) {
            p0 += __shfl_xor(p0, msk); p1 += __shfl_xor(p1, msk);
            p2 += __shfl_xor(p2, msk); ps += __shfl_xor(ps, msk);
        }
        if (lane == 0) {
            disp[(size_t)n * 3 + 0] = p0 + s_b2[0];
            disp[(size_t)n * 3 + 1] = p1 + s_b2[1];
            disp[(size_t)n * 3 + 2] = p2 + s_b2[2];
            float xs = ps + s_b2[3];
            stress[n] = fmaxf(xs, 0.f) + log1pf(expf(-fabsf(xs)));
        }
    }
}

extern "C" void kernel_launch(void* const* d_in, const int* in_sizes, int n_in,
                              void* d_out, int out_size, void* d_ws, size_t ws_size,
                              hipStream_t stream) {
    const float* x = (const float*)d_in[0];
    const int* ei = (const int*)d_in[1];
    const float* ea = (const float*)d_in[2];
    const float* ne_w1 = (const float*)d_in[3];
    const float* ne_b1 = (const float*)d_in[4];
    const float* ne_g1 = (const float*)d_in[5];
    const float* ne_be1 = (const float*)d_in[6];
    const float* ne_w2 = (const float*)d_in[7];
    const float* ne_b2 = (const float*)d_in[8];
    const float* ne_g2 = (const float*)d_in[9];
    const float* ne_be2 = (const float*)d_in[10];
    const float* ee_w1 = (const float*)d_in[11];
    const float* ee_b1 = (const float*)d_in[12];
    const float* ee_g1 = (const float*)d_in[13];
    const float* ee_be1 = (const float*)d_in[14];
    const float* ee_w2 = (const float*)d_in[15];
    const float* ee_b2 = (const float*)d_in[16];
    const float* ee_g2 = (const float*)d_in[17];
    const float* ee_be2 = (const float*)d_in[18];
    const float* cv_w1 = (const float*)d_in[19];
    const float* cv_b1 = (const float*)d_in[20];
    const float* cv_g1 = (const float*)d_in[21];
    const float* cv_be1 = (const float*)d_in[22];
    const float* cv_w2 = (const float*)d_in[23];
    const float* cv_b2 = (const float*)d_in[24];
    const float* cv_g2 = (const float*)d_in[25];
    const float* cv_be2 = (const float*)d_in[26];
    const float* nm_g = (const float*)d_in[27];
    const float* nm_b = (const float*)d_in[28];
    const float* dh_w1 = (const float*)d_in[29];
    const float* dh_b1 = (const float*)d_in[30];
    const float* dh_g = (const float*)d_in[31];
    const float* dh_be = (const float*)d_in[32];
    const float* dh_w2 = (const float*)d_in[33];
    const float* dh_b2 = (const float*)d_in[34];
    const float* sh_w1 = (const float*)d_in[35];
    const float* sh_b1 = (const float*)d_in[36];
    const float* sh_g = (const float*)d_in[37];
    const float* sh_be = (const float*)d_in[38];
    const float* sh_w2 = (const float*)d_in[39];
    const float* sh_b2 = (const float*)d_in[40];

    int N = in_sizes[0] / 6;
    int E = in_sizes[1] / 2;

    char* wp = (char*)d_ws;
    auto take = [&](size_t bytes) {
        char* p = wp;
        wp += (bytes + 255) & ~(size_t)255;
        return p;
    };
    unsigned short* e_perm = (unsigned short*)take((size_t)E * HD * 2);   // 204.8 MB
    float* h0 = (float*)take((size_t)N * HD * 4);                          // 25.6 MB
    float* h1 = (float*)take((size_t)N * HD * 4);                          // 25.6 MB
    unsigned short* wbf = (unsigned short*)take((size_t)10 * HD * HD * 2);
    int* cnt = (int*)take((size_t)N * 4);
    int* offs = (int*)take((size_t)(N + 1) * 4);
    int* cursor = (int*)take((size_t)N * 4);
    int* bsum = (int*)take(256);
    int* pos = (int*)take((size_t)E * 4);
    int* esrc = (int*)take((size_t)E * 4);

    const int* srcArr = ei;
    const int* dstArr = ei + E;

    int nbN = (N + TILE - 1) / TILE;
    int nbE = (E + TILE - 1) / TILE;

    prep_weights<<<10, 256, 0, stream>>>(ne_w2, ee_w2, cv_w1, cv_w2, wbf);
    zero_kernel<<<(N + 255) / 256, 256, 0, stream>>>(cnt, N);
    hist_kernel<<<2048, 256, 0, stream>>>(dstArr, cnt, E);
    int nsb = (N + 1023) / 1024;
    scan_block_kernel<<<nsb, 1024, 0, stream>>>(cnt, offs + 1, bsum, N);
    scan_top_kernel<<<1, 64, 0, stream>>>(bsum, nsb);
    add_off_kernel<<<(N + 255) / 256, 256, 0, stream>>>(offs, bsum, cursor, N);
    scatter_kernel<<<2048, 256, 0, stream>>>(srcArr, dstArr, cursor, pos, esrc, E);

    encoder_mfma<6, false><<<nbN, 256, 0, stream>>>(
        x, ne_w1, ne_b1, ne_g1, ne_be1, wbf + 0 * HD * HD, ne_b2, ne_g2, ne_be2,
        h0, nullptr, nullptr, N);
    encoder_mfma<4, true><<<nbE, 256, 0, stream>>>(
        ea, ee_w1, ee_b1, ee_g1, ee_be1, wbf + 1 * HD * HD, ee_b2, ee_g2, ee_be2,
        nullptr, e_perm, pos, E);

    float* hbuf[2] = {h0, h1};
    for (int l = 0; l < 4; ++l) {
        float* h_old = hbuf[l & 1];
        float* h_new = hbuf[(l + 1) & 1];
        agg_conv_mfma<<<nbN, 256, 0, stream>>>(
            h_old, h_new, e_perm, offs, esrc, wbf + (size_t)(2 + l) * HD * HD,
            cv_b1 + l * HD, cv_g1 + l * HD, cv_be1 + l * HD,
            wbf + (size_t)(6 + l) * HD * HD, cv_b2 + l * HD, cv_g2 + l * HD,
            cv_be2 + l * HD, nm_g + l * HD, nm_b + l * HD, N);
    }

    head_kernel<<<1024, 256, 0, stream>>>(h0, dh_w1, dh_b1, dh_g, dh_be, dh_w2, dh_b2,
                                          sh_w1, sh_b1, sh_g, sh_be, sh_w2, sh_b2,
                                          (float*)d_out, N);
}

// Round 13
// 941.204 us; speedup vs baseline: 1.1459x; 1.1459x over previous
//
#include <hip/hip_runtime.h>
#include <hip/hip_bf16.h>
#include <hip/hip_fp16.h>

#define HD 128
#define TILE 64
#define ST 136  // LDS row stride in bf16 (272B; b128/b64 access -> 2-way bank alias, free)

typedef __attribute__((ext_vector_type(8))) short bf16x8;
typedef __attribute__((ext_vector_type(4))) float f32x4;

// fast GELU (A&S 7.1.26, |eps|<=1.5e-7). Safe only with the hi/lo tin pair (R8):
// the single-plane tin->bf16 quantizer amplified 1e-6 perturbations into 0.25
// absmax failures (R3/R4/R6).
__device__ __forceinline__ float gelu_f(float x) {
    float y = fabsf(x) * 0.70710678118654752f;
    float t = __builtin_amdgcn_rcpf(fmaf(0.3275911f, y, 1.0f));
    float p = t * fmaf(t, fmaf(t, fmaf(t, fmaf(t, 1.061405429f, -1.453152027f),
                                       1.421413741f), -0.284496736f), 0.254829592f);
    float E = fmaf(-p, __expf(-y * y), 1.0f);
    return 0.5f * x * (1.0f + copysignf(E, x));
}
__device__ __forceinline__ unsigned short f2bf(float f) {
    unsigned int x = __float_as_uint(f);
    x = x + 0x7fffu + ((x >> 16) & 1u);
    return (unsigned short)(x >> 16);
}
__device__ __forceinline__ unsigned int pk2bf(float lo, float hi) {
    return (unsigned int)f2bf(lo) | ((unsigned int)f2bf(hi) << 16);
}
__device__ __forceinline__ float bf2f(unsigned short u) {
    return __uint_as_float((unsigned int)u << 16);
}
// fp16 pack/unpack (RNE) — e_perm storage only (never feeds MFMA)
__device__ __forceinline__ unsigned int pk2h(float lo, float hi) {
    return (unsigned int)__half_as_ushort(__float2half(lo)) |
           ((unsigned int)__half_as_ushort(__float2half(hi)) << 16);
}
__device__ __forceinline__ float h2f_lo(unsigned int u) {
    return __half2float(__ushort_as_half((unsigned short)(u & 0xffffu)));
}
__device__ __forceinline__ float h2f_hi(unsigned int u) {
    return __half2float(__ushort_as_half((unsigned short)(u >> 16)));
}

// OPERAND-SWAPPED MFMA: D = Wt_frag (A-op) x X_frag (B-op).
// wt layout: wt[((n0*4+kk)*64+l)*8+e] = W[kk*32+(l>>4)*8+e][n0*16+(l&15)]
// Result: acc[n0][q] = u[node wrow+(l&15)][feature n0*16+(l>>4)*4+q]
__device__ __forceinline__ void mm_mfma(const unsigned short* sA, int wrow, int lane,
                                        const unsigned short* __restrict__ wt, f32x4 acc[8]) {
    int m = lane & 15, kb = lane >> 4;
    bf16x8 a[4];
#pragma unroll
    for (int kk = 0; kk < 4; ++kk)
        a[kk] = *(const bf16x8*)(sA + (wrow + m) * ST + kk * 32 + kb * 8);
#pragma unroll
    for (int n0 = 0; n0 < 8; ++n0) {
        f32x4 c = {0.f, 0.f, 0.f, 0.f};
#pragma unroll
        for (int kk = 0; kk < 4; ++kk) {
            bf16x8 b = *(const bf16x8*)(wt + ((size_t)((n0 * 4 + kk) * 64 + lane)) * 8);
            c = __builtin_amdgcn_mfma_f32_16x16x32_bf16(b, a[kk], c, 0, 0, 0);
        }
        acc[n0] = c;
    }
}

// two-plane (hi+lo): acc = W^T x (Hi + Lo), chained accumulation
__device__ __forceinline__ void mm_mfma2(const unsigned short* sH, const unsigned short* sL,
                                         int wrow, int lane,
                                         const unsigned short* __restrict__ wt, f32x4 acc[8]) {
    int m = lane & 15, kb = lane >> 4;
    bf16x8 ah[4], al[4];
#pragma unroll
    for (int kk = 0; kk < 4; ++kk) {
        ah[kk] = *(const bf16x8*)(sH + (wrow + m) * ST + kk * 32 + kb * 8);
        al[kk] = *(const bf16x8*)(sL + (wrow + m) * ST + kk * 32 + kb * 8);
    }
#pragma unroll
    for (int n0 = 0; n0 < 8; ++n0) {
        f32x4 c = {0.f, 0.f, 0.f, 0.f};
#pragma unroll
        for (int kk = 0; kk < 4; ++kk) {
            bf16x8 b = *(const bf16x8*)(wt + ((size_t)((n0 * 4 + kk) * 64 + lane)) * 8);
            c = __builtin_amdgcn_mfma_f32_16x16x32_bf16(b, ah[kk], c, 0, 0, 0);
            c = __builtin_amdgcn_mfma_f32_16x16x32_bf16(b, al[kk], c, 0, 0, 0);
        }
        acc[n0] = c;
    }
}

// bias + LN + GELU for the swapped C-layout: lane owns node wrow+m, 32 values
// u[n0][q] = feature n0*16+kb*4+q. Row-reduce = local sum + xor16/xor32.
__device__ __forceinline__ void bias_ln_gelu(f32x4 acc[8], float u[8][4],
                                             const float* bias, const float* g,
                                             const float* be, int kb) {
    float s = 0.f, ss = 0.f;
#pragma unroll
    for (int n0 = 0; n0 < 8; ++n0)
#pragma unroll
        for (int q = 0; q < 4; ++q) {
            float x = acc[n0][q] + bias[n0 * 16 + kb * 4 + q];
            u[n0][q] = x;
            s += x; ss += x * x;
        }
    s += __shfl_xor(s, 16); ss += __shfl_xor(ss, 16);
    s += __shfl_xor(s, 32); ss += __shfl_xor(ss, 32);
    float mean = s * (1.f / HD);
    float inv = rsqrtf(ss * (1.f / HD) - mean * mean + 1e-5f);
#pragma unroll
    for (int n0 = 0; n0 < 8; ++n0)
#pragma unroll
        for (int q = 0; q < 4; ++q) {
            int c = n0 * 16 + kb * 4 + q;
            u[n0][q] = gelu_f((u[n0][q] - mean) * inv * g[c] + be[c]);
        }
}

// ---------------- weight prep: bf16 + MFMA-fragment order (10 matrices 128x128)
__global__ void prep_weights(const float* __restrict__ ne_w2, const float* __restrict__ ee_w2,
                             const float* __restrict__ cv_w1, const float* __restrict__ cv_w2,
                             unsigned short* __restrict__ wbf) {
    int mat = blockIdx.x;
    const float* src = (mat == 0) ? ne_w2
                     : (mat == 1) ? ee_w2
                     : (mat < 6)  ? cv_w1 + (size_t)(mat - 2) * HD * HD
                                  : cv_w2 + (size_t)(mat - 6) * HD * HD;
    unsigned short* dst = wbf + (size_t)mat * HD * HD;
    for (int i = threadIdx.x; i < HD * HD; i += 256) {
        int e = i & 7, lane = (i >> 3) & 63, f = i >> 9;  // f = n0*4+kk
        int m = lane & 15, kb = lane >> 4;
        int n0 = f >> 2, kk = f & 3;
        int k = kk * 32 + kb * 8 + e;
        int c = n0 * 16 + m;
        dst[i] = f2bf(src[(size_t)k * HD + c]);
    }
}

// ---------------- encoder: Linear(IN_DIM->128)+LN+GELU, MFMA Linear(128->128)+LN+GELU
template <int IN_DIM, bool EDGE>
__global__ __launch_bounds__(256) void encoder_mfma(
    const float* __restrict__ in, const float* __restrict__ w1,
    const float* __restrict__ b1, const float* __restrict__ g1,
    const float* __restrict__ be1, const unsigned short* __restrict__ wt2,
    const float* __restrict__ b2, const float* __restrict__ g2,
    const float* __restrict__ be2, float* __restrict__ h_out,
    unsigned short* __restrict__ e_perm, const int* __restrict__ pos, int rows) {
    __shared__ __align__(16) unsigned short s_A[TILE * ST];
    __shared__ float s_vec[6][HD];
    __shared__ int s_pos[TILE];

    int tid = threadIdx.x;
    int row0 = blockIdx.x * TILE;
    if (tid < HD) {
        s_vec[0][tid] = b1[tid]; s_vec[1][tid] = g1[tid]; s_vec[2][tid] = be1[tid];
        s_vec[3][tid] = b2[tid]; s_vec[4][tid] = g2[tid]; s_vec[5][tid] = be2[tid];
    }
    if (EDGE && tid < TILE) {
        int gr = row0 + tid;
        s_pos[tid] = (gr < rows) ? pos[gr] : 0;
    }
    __syncthreads();

    // phase A: thread (tr,tc) owns rows r0..r0+3, cols c0..c0+7; w1 in registers
    int tr = tid >> 4, tc = tid & 15;
    int r0 = tr * 4, c0 = tc * 8;
    float w1r[IN_DIM][8];
#pragma unroll
    for (int k = 0; k < IN_DIM; ++k) {
        float4 pa = *(const float4*)(w1 + (size_t)k * HD + c0);
        float4 pb = *(const float4*)(w1 + (size_t)k * HD + c0 + 4);
        w1r[k][0] = pa.x; w1r[k][1] = pa.y; w1r[k][2] = pa.z; w1r[k][3] = pa.w;
        w1r[k][4] = pb.x; w1r[k][5] = pb.y; w1r[k][6] = pb.z; w1r[k][7] = pb.w;
    }
    float v[4][8];
#pragma unroll
    for (int i = 0; i < 4; ++i)
#pragma unroll
        for (int j = 0; j < 8; ++j) v[i][j] = s_vec[0][c0 + j];
#pragma unroll
    for (int i = 0; i < 4; ++i) {
        int gr = min(row0 + r0 + i, rows - 1);
        float xr[IN_DIM];
        if constexpr (IN_DIM == 4) {
            float4 t4 = *(const float4*)(in + (size_t)gr * 4);
            xr[0] = t4.x; xr[1] = t4.y; xr[2] = t4.z; xr[3] = t4.w;
        } else {
#pragma unroll
            for (int k = 0; k < IN_DIM; ++k) xr[k] = in[(size_t)gr * IN_DIM + k];
        }
#pragma unroll
        for (int k = 0; k < IN_DIM; ++k)
#pragma unroll
            for (int j = 0; j < 8; ++j) v[i][j] = fmaf(xr[k], w1r[k][j], v[i][j]);
    }
    // LN+GELU per row (16-lane tc groups), pack to LDS
#pragma unroll
    for (int i = 0; i < 4; ++i) {
        float s = 0.f, ss = 0.f;
#pragma unroll
        for (int j = 0; j < 8; ++j) { s += v[i][j]; ss += v[i][j] * v[i][j]; }
#pragma unroll
        for (int msk = 1; msk < 16; msk <<= 1) { s += __shfl_xor(s, msk); ss += __shfl_xor(ss, msk); }
        float mean = s * (1.f / HD);
        float inv = rsqrtf(ss * (1.f / HD) - mean * mean + 1e-5f);
#pragma unroll
        for (int j = 0; j < 8; ++j)
            v[i][j] = gelu_f((v[i][j] - mean) * inv * s_vec[1][c0 + j] + s_vec[2][c0 + j]);
        uint4 q4;
        q4.x = pk2bf(v[i][0], v[i][1]); q4.y = pk2bf(v[i][2], v[i][3]);
        q4.z = pk2bf(v[i][4], v[i][5]); q4.w = pk2bf(v[i][6], v[i][7]);
        *(uint4*)&s_A[(r0 + i) * ST + c0] = q4;
    }
    __syncthreads();

    // phase B: swapped MFMA -> lane owns node wrow+m, features n0*16+kb*4+q
    int wave = tid >> 6, lane = tid & 63;
    int m = lane & 15, kb = lane >> 4;
    int wrow = wave * 16;
    f32x4 acc[8];
    mm_mfma(s_A, wrow, lane, wt2, acc);
    float u[8][4];
    bias_ln_gelu(acc, u, s_vec[3], s_vec[4], s_vec[5], kb);

    if (EDGE) {
        __syncthreads();  // all B-frag LDS reads complete before overwrite
        // stage output as FP16 (e_perm storage dtype; never feeds MFMA)
#pragma unroll
        for (int n0 = 0; n0 < 8; ++n0) {
            uint2 p;
            p.x = pk2h(u[n0][0], u[n0][1]);
            p.y = pk2h(u[n0][2], u[n0][3]);
            *(uint2*)&s_A[(wrow + m) * ST + n0 * 16 + kb * 4] = p;
        }
        __syncthreads();
#pragma unroll
        for (int i = 0; i < 4; ++i) {
            int c = tid + i * 256;  // 1024 chunks of 8 fp16
            int r = c >> 4, cc = (c & 15) * 8;
            int gr = row0 + r;
            if (gr < rows) {
                uint4 q4 = *(uint4*)&s_A[r * ST + cc];
                *(uint4*)(e_perm + (size_t)s_pos[r] * HD + cc) = q4;
            }
        }
    } else {
        int grow = row0 + wrow + m;
        if (grow < rows) {
#pragma unroll
            for (int n0 = 0; n0 < 8; ++n0)
                *(float4*)(h_out + (size_t)grow * HD + n0 * 16 + kb * 4) =
                    make_float4(u[n0][0], u[n0][1], u[n0][2], u[n0][3]);
        }
    }
}

// ---------------- GINE conv block: u = block(tin_hi+tin_lo); h += gelu(ln(u, nm))
__global__ __launch_bounds__(256) void conv_mfma(
    const unsigned short* __restrict__ tin_hi, const unsigned short* __restrict__ tin_lo,
    float* __restrict__ h,
    const unsigned short* __restrict__ wt1, const float* __restrict__ b1,
    const float* __restrict__ g1, const float* __restrict__ be1,
    const unsigned short* __restrict__ wt2, const float* __restrict__ b2,
    const float* __restrict__ g2, const float* __restrict__ be2,
    const float* __restrict__ nmg, const float* __restrict__ nmb, int rows) {
    __shared__ __align__(16) unsigned short s_A[TILE * ST];
    __shared__ __align__(16) unsigned short s_L[TILE * ST];
    __shared__ float s_vec[8][HD];

    int tid = threadIdx.x;
    int row0 = blockIdx.x * TILE;
    if (tid < HD) {
        s_vec[0][tid] = b1[tid];  s_vec[1][tid] = g1[tid];  s_vec[2][tid] = be1[tid];
        s_vec[3][tid] = b2[tid];  s_vec[4][tid] = g2[tid];  s_vec[5][tid] = be2[tid];
        s_vec[6][tid] = nmg[tid]; s_vec[7][tid] = nmb[tid];
    }
    // stage hi+lo bf16 tin -> LDS (straight 16B copies)
#pragma unroll
    for (int i = 0; i < 4; ++i) {
        int c = tid + i * 256;  // 1024 chunks of 8 bf16
        int r = c >> 4, cc = (c & 15) * 8;
        int gr = min(row0 + r, rows - 1);
        *(uint4*)&s_A[r * ST + cc] = *(const uint4*)(tin_hi + (size_t)gr * HD + cc);
        *(uint4*)&s_L[r * ST + cc] = *(const uint4*)(tin_lo + (size_t)gr * HD + cc);
    }
    __syncthreads();

    int wave = tid >> 6, lane = tid & 63;
    int m = lane & 15, kb = lane >> 4;
    int wrow = wave * 16;
    f32x4 acc[8];
    float u[8][4];

    mm_mfma2(s_A, s_L, wrow, lane, wt1, acc);
    bias_ln_gelu(acc, u, s_vec[0], s_vec[1], s_vec[2], kb);
    __syncthreads();  // all stage-1 LDS reads complete before t1 overwrite
#pragma unroll
    for (int n0 = 0; n0 < 8; ++n0) {
        uint2 p;
        p.x = pk2bf(u[n0][0], u[n0][1]);
        p.y = pk2bf(u[n0][2], u[n0][3]);
        *(uint2*)&s_A[(wrow + m) * ST + n0 * 16 + kb * 4] = p;
    }
    __syncthreads();

    mm_mfma(s_A, wrow, lane, wt2, acc);
    bias_ln_gelu(acc, u, s_vec[3], s_vec[4], s_vec[5], kb);
    // second LN (nm) + GELU, same layout
    {
        float s = 0.f, ss = 0.f;
#pragma unroll
        for (int n0 = 0; n0 < 8; ++n0)
#pragma unroll
            for (int q = 0; q < 4; ++q) { s += u[n0][q]; ss += u[n0][q] * u[n0][q]; }
        s += __shfl_xor(s, 16); ss += __shfl_xor(ss, 16);
        s += __shfl_xor(s, 32); ss += __shfl_xor(ss, 32);
        float mean = s * (1.f / HD);
        float inv = rsqrtf(ss * (1.f / HD) - mean * mean + 1e-5f);
#pragma unroll
        for (int n0 = 0; n0 < 8; ++n0)
#pragma unroll
            for (int q = 0; q < 4; ++q) {
                int c = n0 * 16 + kb * 4 + q;
                u[n0][q] = gelu_f((u[n0][q] - mean) * inv * s_vec[6][c] + s_vec[7][c]);
            }
    }
    int grow = row0 + wrow + m;
    if (grow < rows) {
#pragma unroll
        for (int n0 = 0; n0 < 8; ++n0) {
            size_t idx = (size_t)grow * HD + n0 * 16 + kb * 4;
            float4 hv = *(const float4*)(h + idx);
            hv.x += u[n0][0]; hv.y += u[n0][1]; hv.z += u[n0][2]; hv.w += u[n0][3];
            *(float4*)(h + idx) = hv;
        }
    }
}

// ---------------- CSR build (DETERMINISTIC: segments sorted by edge id) ----------------
__global__ void zero_kernel(int* p, int n) {
    int i = blockIdx.x * 256 + threadIdx.x;
    if (i < n) p[i] = 0;
}
__global__ void hist_kernel(const int* __restrict__ dst, int* __restrict__ cnt, int n) {
    for (int i = blockIdx.x * 256 + threadIdx.x; i < n; i += gridDim.x * 256)
        atomicAdd(&cnt[dst[i]], 1);
}
__global__ __launch_bounds__(1024) void scan_block_kernel(
    const int* __restrict__ cnt, int* __restrict__ incl, int* __restrict__ bsum, int n) {
    __shared__ int buf[2][1024];
    int t = threadIdx.x;
    int i = blockIdx.x * 1024 + t;
    int v = (i < n) ? cnt[i] : 0;
    buf[0][t] = v;
    __syncthreads();
    int pin = 0;
    for (int off = 1; off < 1024; off <<= 1) {
        int x = buf[pin][t];
        if (t >= off) x += buf[pin][t - off];
        buf[pin ^ 1][t] = x;
        __syncthreads();
        pin ^= 1;
    }
    if (i < n) incl[i] = buf[pin][t];
    if (t == 1023) bsum[blockIdx.x] = buf[pin][t];
}
__global__ void scan_top_kernel(int* bsum, int nb) {
    int t = threadIdx.x;  // 64 threads
    int v = (t < nb) ? bsum[t] : 0;
    int orig = v;
#pragma unroll
    for (int off = 1; off < 64; off <<= 1) {
        int y = __shfl_up(v, off);
        if (t >= off) v += y;
    }
    if (t < nb) bsum[t] = v - orig;
}
__global__ void add_off_kernel(int* __restrict__ offs, const int* __restrict__ bsum,
                               int* __restrict__ cursor, int n) {
    int i = blockIdx.x * 256 + threadIdx.x;
    if (i == 0) { offs[0] = 0; cursor[0] = 0; }
    if (i < n) {
        int v = offs[i + 1] + bsum[i >> 10];
        offs[i + 1] = v;
        if (i + 1 < n) cursor[i + 1] = v;
    }
}
// scatter: ticket eids into slots (slot order nondeterministic; fixed by sort below)
__global__ void scatter_kernel(const int* __restrict__ dstArr, int* __restrict__ cursor,
                               int* __restrict__ eidslot, int n) {
    for (int i = blockIdx.x * 256 + threadIdx.x; i < n; i += gridDim.x * 256) {
        int d = dstArr[i];
        int p = atomicAdd(&cursor[d], 1);
        eidslot[p] = i;
    }
}
// insertion-sort each node's segment by eid -> canonical (deterministic) order
__global__ void sort_seg_kernel(const int* __restrict__ offs, int* __restrict__ eidslot, int n) {
    int node = blockIdx.x * 256 + threadIdx.x;
    if (node >= n) return;
    int beg = offs[node], end = offs[node + 1];
    for (int p = beg + 1; p < end; ++p) {
        int v = eidslot[p];
        int q = p - 1;
        while (q >= beg && eidslot[q] > v) { eidslot[q + 1] = eidslot[q]; --q; }
        eidslot[q + 1] = v;
    }
}
// finalize: esrc[p] = src[eid[p]] (in place over eidslot), pos[eid[p]] = p
__global__ void finalize_kernel(const int* __restrict__ srcArr, int* __restrict__ eidslot,
                                int* __restrict__ pos, int n) {
    int p = blockIdx.x * 256 + threadIdx.x;
    if (p < n) {
        int t = eidslot[p];
        pos[t] = p;
        eidslot[p] = srcArr[t];  // becomes esrc
    }
}

// ---------------- aggregate: tin = h + sum relu(h[src]+e)  (h fp32, e FP16 CSR-order)
// unroll-4 batched loads, strictly serial accumulation; writes bf16 hi/lo pair.
__global__ __launch_bounds__(256) void aggregate_kernel(
    const float* __restrict__ h, const unsigned short* __restrict__ e,
    const int* __restrict__ offs, const int* __restrict__ esrc,
    unsigned short* __restrict__ tin_hi, unsigned short* __restrict__ tin_lo, int nnodes) {
    int wave = threadIdx.x >> 6, lane = threadIdx.x & 63;
    int n = blockIdx.x * 4 + wave;
    if (n >= nnodes) return;
    int beg = offs[n], end = offs[n + 1];
    float ax = 0.f, ay = 0.f;
    int i = beg;
    for (; i + 4 <= end; i += 4) {
        int s0 = esrc[i], s1 = esrc[i + 1], s2 = esrc[i + 2], s3 = esrc[i + 3];
        float2 h0 = *(const float2*)(h + (size_t)s0 * HD + 2 * lane);
        float2 h1 = *(const float2*)(h + (size_t)s1 * HD + 2 * lane);
        float2 h2 = *(const float2*)(h + (size_t)s2 * HD + 2 * lane);
        float2 h3 = *(const float2*)(h + (size_t)s3 * HD + 2 * lane);
        unsigned int e0 = *(const unsigned int*)(e + (size_t)(i + 0) * HD + 2 * lane);
        unsigned int e1 = *(const unsigned int*)(e + (size_t)(i + 1) * HD + 2 * lane);
        unsigned int e2 = *(const unsigned int*)(e + (size_t)(i + 2) * HD + 2 * lane);
        unsigned int e3 = *(const unsigned int*)(e + (size_t)(i + 3) * HD + 2 * lane);
        ax += fmaxf(h0.x + h2f_lo(e0), 0.f);
        ay += fmaxf(h0.y + h2f_hi(e0), 0.f);
        ax += fmaxf(h1.x + h2f_lo(e1), 0.f);
        ay += fmaxf(h1.y + h2f_hi(e1), 0.f);
        ax += fmaxf(h2.x + h2f_lo(e2), 0.f);
        ay += fmaxf(h2.y + h2f_hi(e2), 0.f);
        ax += fmaxf(h3.x + h2f_lo(e3), 0.f);
        ay += fmaxf(h3.y + h2f_hi(e3), 0.f);
    }
    for (; i < end; ++i) {
        int src = esrc[i];
        float2 hv = *(const float2*)(h + (size_t)src * HD + 2 * lane);
        unsigned int ue = *(const unsigned int*)(e + (size_t)i * HD + 2 * lane);
        ax += fmaxf(hv.x + h2f_lo(ue), 0.f);
        ay += fmaxf(hv.y + h2f_hi(ue), 0.f);
    }
    float2 hn = *(const float2*)(h + (size_t)n * HD + 2 * lane);
    float tx = hn.x + ax, ty = hn.y + ay;
    unsigned short hx = f2bf(tx), hy = f2bf(ty);
    float lx = tx - bf2f(hx), ly = ty - bf2f(hy);
    *(unsigned int*)(tin_hi + (size_t)n * HD + 2 * lane) =
        (unsigned int)hx | ((unsigned int)hy << 16);
    *(unsigned int*)(tin_lo + (size_t)n * HD + 2 * lane) = pk2bf(lx, ly);
}

// ---------------- heads ----------------
__global__ __launch_bounds__(256) void head_kernel(
    const float* __restrict__ h, const float* __restrict__ dw1,
    const float* __restrict__ db1, const float* __restrict__ dg,
    const float* __restrict__ dbe, const float* __restrict__ dw2,
    const float* __restrict__ db2, const float* __restrict__ sw1,
    const float* __restrict__ sb1, const float* __restrict__ sg,
    const float* __restrict__ sbe, const float* __restrict__ sw2,
    const float* __restrict__ sb2, float* __restrict__ out, int nnodes) {
    __shared__ float s_wd[HD * 64];
    __shared__ float s_ws[HD * 64];
    __shared__ float s_vd[3][64];
    __shared__ float s_vs[3][64];
    __shared__ float s_w2d[64 * 3];
    __shared__ float s_w2s[64];
    __shared__ float s_h[4][HD];
    __shared__ float s_b2[4];

    int tid = threadIdx.x;
    for (int i = tid; i < HD * 64; i += 256) { s_wd[i] = dw1[i]; s_ws[i] = sw1[i]; }
    if (tid < 64) {
        s_vd[0][tid] = db1[tid]; s_vd[1][tid] = dg[tid]; s_vd[2][tid] = dbe[tid];
        s_vs[0][tid] = sb1[tid]; s_vs[1][tid] = sg[tid]; s_vs[2][tid] = sbe[tid];
        s_w2s[tid] = sw2[tid];
    }
    if (tid < 64 * 3) s_w2d[tid] = dw2[tid];
    if (tid == 0) { s_b2[0] = db2[0]; s_b2[1] = db2[1]; s_b2[2] = db2[2]; s_b2[3] = sb2[0]; }
    __syncthreads();

    int wave = tid >> 6, lane = tid & 63;
    float* disp = out;
    float* stress = out + (size_t)nnodes * 3;
    float* hout = out + (size_t)nnodes * 4;

    for (int n = blockIdx.x * 4 + wave; n < nnodes; n += gridDim.x * 4) {
        float2 hv = *(const float2*)(h + (size_t)n * HD + lane * 2);
        *(float2*)(hout + (size_t)n * HD + lane * 2) = hv;
        s_h[wave][lane * 2] = hv.x;
        s_h[wave][lane * 2 + 1] = hv.y;
        float accd = s_vd[0][lane], accs = s_vs[0][lane];
        for (int k = 0; k < HD; ++k) {
            float hx = s_h[wave][k];
            accd = fmaf(hx, s_wd[k * 64 + lane], accd);
            accs = fmaf(hx, s_ws[k * 64 + lane], accs);
        }
        float s = accd, ss = accd * accd;
#pragma unroll
        for (int msk = 1; msk < 64; msk <<= 1) { s += __shfl_xor(s, msk); ss += __shfl_xor(ss, msk); }
        float mean = s * (1.f / 64), inv = rsqrtf(ss * (1.f / 64) - mean * mean + 1e-5f);
        float d = gelu_f((accd - mean) * inv * s_vd[1][lane] + s_vd[2][lane]);
        s = accs; ss = accs * accs;
#pragma unroll
        for (int msk = 1; msk < 64; msk <<= 1) { s += __shfl_xor(s, msk); ss += __shfl_xor(ss, msk); }
        mean = s * (1.f / 64); inv = rsqrtf(ss * (1.f / 64) - mean * mean + 1e-5f);
        float sv = gelu_f((accs - mean) * inv * s_vs[1][lane] + s_vs[2][lane]);
        float p0 = d * s_w2d[lane * 3 + 0];
        float p1 = d * s_w2d[lane * 3 + 1];
        float p2 = d * s_w2d[lane * 3 + 2];
        float ps = sv * s_w2s[lane];
#pragma unroll
        for (int msk = 1; msk < 64; msk <<= 1) {
            p0 += __shfl_xor(p0, msk); p1 += __shfl_xor(p1, msk);
            p2 += __shfl_xor(p2, msk); ps += __shfl_xor(ps, msk);
        }
        if (lane == 0) {
            disp[(size_t)n * 3 + 0] = p0 + s_b2[0];
            disp[(size_t)n * 3 + 1] = p1 + s_b2[1];
            disp[(size_t)n * 3 + 2] = p2 + s_b2[2];
            float xs = ps + s_b2[3];
            stress[n] = fmaxf(xs, 0.f) + log1pf(expf(-fabsf(xs)));
        }
    }
}

extern "C" void kernel_launch(void* const* d_in, const int* in_sizes, int n_in,
                              void* d_out, int out_size, void* d_ws, size_t ws_size,
                              hipStream_t stream) {
    const float* x = (const float*)d_in[0];
    const int* ei = (const int*)d_in[1];
    const float* ea = (const float*)d_in[2];
    const float* ne_w1 = (const float*)d_in[3];
    const float* ne_b1 = (const float*)d_in[4];
    const float* ne_g1 = (const float*)d_in[5];
    const float* ne_be1 = (const float*)d_in[6];
    const float* ne_w2 = (const float*)d_in[7];
    const float* ne_b2 = (const float*)d_in[8];
    const float* ne_g2 = (const float*)d_in[9];
    const float* ne_be2 = (const float*)d_in[10];
    const float* ee_w1 = (const float*)d_in[11];
    const float* ee_b1 = (const float*)d_in[12];
    const float* ee_g1 = (const float*)d_in[13];
    const float* ee_be1 = (const float*)d_in[14];
    const float* ee_w2 = (const float*)d_in[15];
    const float* ee_b2 = (const float*)d_in[16];
    const float* ee_g2 = (const float*)d_in[17];
    const float* ee_be2 = (const float*)d_in[18];
    const float* cv_w1 = (const float*)d_in[19];
    const float* cv_b1 = (const float*)d_in[20];
    const float* cv_g1 = (const float*)d_in[21];
    const float* cv_be1 = (const float*)d_in[22];
    const float* cv_w2 = (const float*)d_in[23];
    const float* cv_b2 = (const float*)d_in[24];
    const float* cv_g2 = (const float*)d_in[25];
    const float* cv_be2 = (const float*)d_in[26];
    const float* nm_g = (const float*)d_in[27];
    const float* nm_b = (const float*)d_in[28];
    const float* dh_w1 = (const float*)d_in[29];
    const float* dh_b1 = (const float*)d_in[30];
    const float* dh_g = (const float*)d_in[31];
    const float* dh_be = (const float*)d_in[32];
    const float* dh_w2 = (const float*)d_in[33];
    const float* dh_b2 = (const float*)d_in[34];
    const float* sh_w1 = (const float*)d_in[35];
    const float* sh_b1 = (const float*)d_in[36];
    const float* sh_g = (const float*)d_in[37];
    const float* sh_be = (const float*)d_in[38];
    const float* sh_w2 = (const float*)d_in[39];
    const float* sh_b2 = (const float*)d_in[40];

    int N = in_sizes[0] / 6;
    int E = in_sizes[1] / 2;

    char* wp = (char*)d_ws;
    auto take = [&](size_t bytes) {
        char* p = wp;
        wp += (bytes + 255) & ~(size_t)255;
        return p;
    };
    unsigned short* e_perm = (unsigned short*)take((size_t)E * HD * 2);   // 204.8 MB (fp16)
    float* h = (float*)take((size_t)N * HD * 4);                           // 25.6 MB
    unsigned short* tin_hi = (unsigned short*)take((size_t)N * HD * 2);    // 12.8 MB
    unsigned short* tin_lo = (unsigned short*)take((size_t)N * HD * 2);    // 12.8 MB
    unsigned short* wbf = (unsigned short*)take((size_t)10 * HD * HD * 2);
    int* cnt = (int*)take((size_t)N * 4);
    int* offs = (int*)take((size_t)(N + 1) * 4);
    int* cursor = (int*)take((size_t)N * 4);
    int* bsum = (int*)take(256);
    int* pos = (int*)take((size_t)E * 4);
    int* esrc = (int*)take((size_t)E * 4);  // holds eids during CSR build, then srcs

    const int* srcArr = ei;
    const int* dstArr = ei + E;

    int nbN = (N + TILE - 1) / TILE;
    int nbE = (E + TILE - 1) / TILE;

    prep_weights<<<10, 256, 0, stream>>>(ne_w2, ee_w2, cv_w1, cv_w2, wbf);
    zero_kernel<<<(N + 255) / 256, 256, 0, stream>>>(cnt, N);
    hist_kernel<<<2048, 256, 0, stream>>>(dstArr, cnt, E);
    int nsb = (N + 1023) / 1024;
    scan_block_kernel<<<nsb, 1024, 0, stream>>>(cnt, offs + 1, bsum, N);
    scan_top_kernel<<<1, 64, 0, stream>>>(bsum, nsb);
    add_off_kernel<<<(N + 255) / 256, 256, 0, stream>>>(offs, bsum, cursor, N);
    scatter_kernel<<<2048, 256, 0, stream>>>(dstArr, cursor, esrc, E);
    sort_seg_kernel<<<(N + 255) / 256, 256, 0, stream>>>(offs, esrc, N);
    finalize_kernel<<<(E + 255) / 256, 256, 0, stream>>>(srcArr, esrc, pos, E);

    encoder_mfma<6, false><<<nbN, 256, 0, stream>>>(
        x, ne_w1, ne_b1, ne_g1, ne_be1, wbf + 0 * HD * HD, ne_b2, ne_g2, ne_be2,
        h, nullptr, nullptr, N);
    encoder_mfma<4, true><<<nbE, 256, 0, stream>>>(
        ea, ee_w1, ee_b1, ee_g1, ee_be1, wbf + 1 * HD * HD, ee_b2, ee_g2, ee_be2,
        nullptr, e_perm, pos, E);

    for (int l = 0; l < 4; ++l) {
        aggregate_kernel<<<(N + 3) / 4, 256, 0, stream>>>(h, e_perm, offs, esrc,
                                                          tin_hi, tin_lo, N);
        conv_mfma<<<nbN, 256, 0, stream>>>(
            tin_hi, tin_lo, h, wbf + (size_t)(2 + l) * HD * HD, cv_b1 + l * HD,
            cv_g1 + l * HD, cv_be1 + l * HD, wbf + (size_t)(6 + l) * HD * HD,
            cv_b2 + l * HD, cv_g2 + l * HD, cv_be2 + l * HD,
            nm_g + l * HD, nm_b + l * HD, N);
    }

    head_kernel<<<1024, 256, 0, stream>>>(h, dh_w1, dh_b1, dh_g, dh_be, dh_w2, dh_b2,
                                          sh_w1, sh_b1, sh_g, sh_be, sh_w2, sh_b2,
                                          (float*)d_out, N);
}

// Round 14
// 859.576 us; speedup vs baseline: 1.2547x; 1.0950x over previous
//
#include <hip/hip_runtime.h>
#include <hip/hip_bf16.h>
#include <hip/hip_fp16.h>

#define HD 128
#define TILE 64
#define ST 136  // LDS row stride in bf16 (272B; b128/b64 access -> 2-way bank alias, free)

typedef __attribute__((ext_vector_type(8))) short bf16x8;
typedef __attribute__((ext_vector_type(4))) float f32x4;

// fast GELU (A&S 7.1.26, |eps|<=1.5e-7). Safe only with the hi/lo tin pair (R8):
// the single-plane tin->bf16 quantizer amplified 1e-6 perturbations into 0.25
// absmax failures (R3/R4/R6).
__device__ __forceinline__ float gelu_f(float x) {
    float y = fabsf(x) * 0.70710678118654752f;
    float t = __builtin_amdgcn_rcpf(fmaf(0.3275911f, y, 1.0f));
    float p = t * fmaf(t, fmaf(t, fmaf(t, fmaf(t, 1.061405429f, -1.453152027f),
                                       1.421413741f), -0.284496736f), 0.254829592f);
    float E = fmaf(-p, __expf(-y * y), 1.0f);
    return 0.5f * x * (1.0f + copysignf(E, x));
}
__device__ __forceinline__ unsigned short f2bf(float f) {
    unsigned int x = __float_as_uint(f);
    x = x + 0x7fffu + ((x >> 16) & 1u);
    return (unsigned short)(x >> 16);
}
__device__ __forceinline__ unsigned int pk2bf(float lo, float hi) {
    return (unsigned int)f2bf(lo) | ((unsigned int)f2bf(hi) << 16);
}
__device__ __forceinline__ float bf2f(unsigned short u) {
    return __uint_as_float((unsigned int)u << 16);
}
// fp16 helpers (RNE) — storage dtypes only (never feed MFMA)
__device__ __forceinline__ unsigned int pk2h(float lo, float hi) {
    return (unsigned int)__half_as_ushort(__float2half(lo)) |
           ((unsigned int)__half_as_ushort(__float2half(hi)) << 16);
}
__device__ __forceinline__ float h2f_lo(unsigned int u) {
    return __half2float(__ushort_as_half((unsigned short)(u & 0xffffu)));
}
__device__ __forceinline__ float h2f_hi(unsigned int u) {
    return __half2float(__ushort_as_half((unsigned short)(u >> 16)));
}
// split fp32 -> fp16 hi + fp16 residual (combined ~22-bit accuracy)
__device__ __forceinline__ void split_h(float v, unsigned short& hi, unsigned short& lo) {
    __half hh = __float2half(v);
    hi = __half_as_ushort(hh);
    lo = __half_as_ushort(__float2half(v - __half2float(hh)));
}

// OPERAND-SWAPPED MFMA: D = Wt_frag (A-op) x X_frag (B-op).
// wt layout: wt[((n0*4+kk)*64+l)*8+e] = W[kk*32+(l>>4)*8+e][n0*16+(l&15)]
// Result: acc[n0][q] = u[node wrow+(l&15)][feature n0*16+(l>>4)*4+q]
__device__ __forceinline__ void mm_mfma(const unsigned short* sA, int wrow, int lane,
                                        const unsigned short* __restrict__ wt, f32x4 acc[8]) {
    int m = lane & 15, kb = lane >> 4;
    bf16x8 a[4];
#pragma unroll
    for (int kk = 0; kk < 4; ++kk)
        a[kk] = *(const bf16x8*)(sA + (wrow + m) * ST + kk * 32 + kb * 8);
#pragma unroll
    for (int n0 = 0; n0 < 8; ++n0) {
        f32x4 c = {0.f, 0.f, 0.f, 0.f};
#pragma unroll
        for (int kk = 0; kk < 4; ++kk) {
            bf16x8 b = *(const bf16x8*)(wt + ((size_t)((n0 * 4 + kk) * 64 + lane)) * 8);
            c = __builtin_amdgcn_mfma_f32_16x16x32_bf16(b, a[kk], c, 0, 0, 0);
        }
        acc[n0] = c;
    }
}

// two-plane (hi+lo): acc = W^T x (Hi + Lo), chained accumulation
__device__ __forceinline__ void mm_mfma2(const unsigned short* sH, const unsigned short* sL,
                                         int wrow, int lane,
                                         const unsigned short* __restrict__ wt, f32x4 acc[8]) {
    int m = lane & 15, kb = lane >> 4;
    bf16x8 ah[4], al[4];
#pragma unroll
    for (int kk = 0; kk < 4; ++kk) {
        ah[kk] = *(const bf16x8*)(sH + (wrow + m) * ST + kk * 32 + kb * 8);
        al[kk] = *(const bf16x8*)(sL + (wrow + m) * ST + kk * 32 + kb * 8);
    }
#pragma unroll
    for (int n0 = 0; n0 < 8; ++n0) {
        f32x4 c = {0.f, 0.f, 0.f, 0.f};
#pragma unroll
        for (int kk = 0; kk < 4; ++kk) {
            bf16x8 b = *(const bf16x8*)(wt + ((size_t)((n0 * 4 + kk) * 64 + lane)) * 8);
            c = __builtin_amdgcn_mfma_f32_16x16x32_bf16(b, ah[kk], c, 0, 0, 0);
            c = __builtin_amdgcn_mfma_f32_16x16x32_bf16(b, al[kk], c, 0, 0, 0);
        }
        acc[n0] = c;
    }
}

// bias + LN + GELU for the swapped C-layout: lane owns node wrow+m, 32 values
// u[n0][q] = feature n0*16+kb*4+q. Row-reduce = local sum + xor16/xor32.
__device__ __forceinline__ void bias_ln_gelu(f32x4 acc[8], float u[8][4],
                                             const float* bias, const float* g,
                                             const float* be, int kb) {
    float s = 0.f, ss = 0.f;
#pragma unroll
    for (int n0 = 0; n0 < 8; ++n0)
#pragma unroll
        for (int q = 0; q < 4; ++q) {
            float x = acc[n0][q] + bias[n0 * 16 + kb * 4 + q];
            u[n0][q] = x;
            s += x; ss += x * x;
        }
    s += __shfl_xor(s, 16); ss += __shfl_xor(ss, 16);
    s += __shfl_xor(s, 32); ss += __shfl_xor(ss, 32);
    float mean = s * (1.f / HD);
    float inv = rsqrtf(ss * (1.f / HD) - mean * mean + 1e-5f);
#pragma unroll
    for (int n0 = 0; n0 < 8; ++n0)
#pragma unroll
        for (int q = 0; q < 4; ++q) {
            int c = n0 * 16 + kb * 4 + q;
            u[n0][q] = gelu_f((u[n0][q] - mean) * inv * g[c] + be[c]);
        }
}

// ---------------- weight prep: bf16 + MFMA-fragment order (10 matrices 128x128)
__global__ void prep_weights(const float* __restrict__ ne_w2, const float* __restrict__ ee_w2,
                             const float* __restrict__ cv_w1, const float* __restrict__ cv_w2,
                             unsigned short* __restrict__ wbf) {
    int mat = blockIdx.x;
    const float* src = (mat == 0) ? ne_w2
                     : (mat == 1) ? ee_w2
                     : (mat < 6)  ? cv_w1 + (size_t)(mat - 2) * HD * HD
                                  : cv_w2 + (size_t)(mat - 6) * HD * HD;
    unsigned short* dst = wbf + (size_t)mat * HD * HD;
    for (int i = threadIdx.x; i < HD * HD; i += 256) {
        int e = i & 7, lane = (i >> 3) & 63, f = i >> 9;  // f = n0*4+kk
        int m = lane & 15, kb = lane >> 4;
        int n0 = f >> 2, kk = f & 3;
        int k = kk * 32 + kb * 8 + e;
        int c = n0 * 16 + m;
        dst[i] = f2bf(src[(size_t)k * HD + c]);
    }
}

// ---------------- encoder: Linear(IN_DIM->128)+LN+GELU, MFMA Linear(128->128)+LN+GELU
template <int IN_DIM, bool EDGE>
__global__ __launch_bounds__(256) void encoder_mfma(
    const float* __restrict__ in, const float* __restrict__ w1,
    const float* __restrict__ b1, const float* __restrict__ g1,
    const float* __restrict__ be1, const unsigned short* __restrict__ wt2,
    const float* __restrict__ b2, const float* __restrict__ g2,
    const float* __restrict__ be2, unsigned short* __restrict__ h_hi,
    unsigned short* __restrict__ h_lo, unsigned short* __restrict__ e_perm,
    const int* __restrict__ pos, int rows) {
    __shared__ __align__(16) unsigned short s_A[TILE * ST];
    __shared__ float s_vec[6][HD];
    __shared__ int s_pos[TILE];

    int tid = threadIdx.x;
    int row0 = blockIdx.x * TILE;
    if (tid < HD) {
        s_vec[0][tid] = b1[tid]; s_vec[1][tid] = g1[tid]; s_vec[2][tid] = be1[tid];
        s_vec[3][tid] = b2[tid]; s_vec[4][tid] = g2[tid]; s_vec[5][tid] = be2[tid];
    }
    if (EDGE && tid < TILE) {
        int gr = row0 + tid;
        s_pos[tid] = (gr < rows) ? pos[gr] : 0;
    }
    __syncthreads();

    // phase A: thread (tr,tc) owns rows r0..r0+3, cols c0..c0+7; w1 in registers
    int tr = tid >> 4, tc = tid & 15;
    int r0 = tr * 4, c0 = tc * 8;
    float w1r[IN_DIM][8];
#pragma unroll
    for (int k = 0; k < IN_DIM; ++k) {
        float4 pa = *(const float4*)(w1 + (size_t)k * HD + c0);
        float4 pb = *(const float4*)(w1 + (size_t)k * HD + c0 + 4);
        w1r[k][0] = pa.x; w1r[k][1] = pa.y; w1r[k][2] = pa.z; w1r[k][3] = pa.w;
        w1r[k][4] = pb.x; w1r[k][5] = pb.y; w1r[k][6] = pb.z; w1r[k][7] = pb.w;
    }
    float v[4][8];
#pragma unroll
    for (int i = 0; i < 4; ++i)
#pragma unroll
        for (int j = 0; j < 8; ++j) v[i][j] = s_vec[0][c0 + j];
#pragma unroll
    for (int i = 0; i < 4; ++i) {
        int gr = min(row0 + r0 + i, rows - 1);
        float xr[IN_DIM];
        if constexpr (IN_DIM == 4) {
            float4 t4 = *(const float4*)(in + (size_t)gr * 4);
            xr[0] = t4.x; xr[1] = t4.y; xr[2] = t4.z; xr[3] = t4.w;
        } else {
#pragma unroll
            for (int k = 0; k < IN_DIM; ++k) xr[k] = in[(size_t)gr * IN_DIM + k];
        }
#pragma unroll
        for (int k = 0; k < IN_DIM; ++k)
#pragma unroll
            for (int j = 0; j < 8; ++j) v[i][j] = fmaf(xr[k], w1r[k][j], v[i][j]);
    }
    // LN+GELU per row (16-lane tc groups), pack to LDS
#pragma unroll
    for (int i = 0; i < 4; ++i) {
        float s = 0.f, ss = 0.f;
#pragma unroll
        for (int j = 0; j < 8; ++j) { s += v[i][j]; ss += v[i][j] * v[i][j]; }
#pragma unroll
        for (int msk = 1; msk < 16; msk <<= 1) { s += __shfl_xor(s, msk); ss += __shfl_xor(ss, msk); }
        float mean = s * (1.f / HD);
        float inv = rsqrtf(ss * (1.f / HD) - mean * mean + 1e-5f);
#pragma unroll
        for (int j = 0; j < 8; ++j)
            v[i][j] = gelu_f((v[i][j] - mean) * inv * s_vec[1][c0 + j] + s_vec[2][c0 + j]);
        uint4 q4;
        q4.x = pk2bf(v[i][0], v[i][1]); q4.y = pk2bf(v[i][2], v[i][3]);
        q4.z = pk2bf(v[i][4], v[i][5]); q4.w = pk2bf(v[i][6], v[i][7]);
        *(uint4*)&s_A[(r0 + i) * ST + c0] = q4;
    }
    __syncthreads();

    // phase B: swapped MFMA -> lane owns node wrow+m, features n0*16+kb*4+q
    int wave = tid >> 6, lane = tid & 63;
    int m = lane & 15, kb = lane >> 4;
    int wrow = wave * 16;
    f32x4 acc[8];
    mm_mfma(s_A, wrow, lane, wt2, acc);
    float u[8][4];
    bias_ln_gelu(acc, u, s_vec[3], s_vec[4], s_vec[5], kb);

    if (EDGE) {
        __syncthreads();  // all B-frag LDS reads complete before overwrite
        // stage output as FP16 (e_perm storage dtype; never feeds MFMA)
#pragma unroll
        for (int n0 = 0; n0 < 8; ++n0) {
            uint2 p;
            p.x = pk2h(u[n0][0], u[n0][1]);
            p.y = pk2h(u[n0][2], u[n0][3]);
            *(uint2*)&s_A[(wrow + m) * ST + n0 * 16 + kb * 4] = p;
        }
        __syncthreads();
#pragma unroll
        for (int i = 0; i < 4; ++i) {
            int c = tid + i * 256;  // 1024 chunks of 8 fp16
            int r = c >> 4, cc = (c & 15) * 8;
            int gr = row0 + r;
            if (gr < rows) {
                uint4 q4 = *(uint4*)&s_A[r * ST + cc];
                *(uint4*)(e_perm + (size_t)s_pos[r] * HD + cc) = q4;
            }
        }
    } else {
        int grow = row0 + wrow + m;
        if (grow < rows) {
#pragma unroll
            for (int n0 = 0; n0 < 8; ++n0) {
                size_t idx = (size_t)grow * HD + n0 * 16 + kb * 4;
                unsigned short hi0, lo0, hi1, lo1, hi2, lo2, hi3, lo3;
                split_h(u[n0][0], hi0, lo0); split_h(u[n0][1], hi1, lo1);
                split_h(u[n0][2], hi2, lo2); split_h(u[n0][3], hi3, lo3);
                uint2 ph, pl;
                ph.x = (unsigned int)hi0 | ((unsigned int)hi1 << 16);
                ph.y = (unsigned int)hi2 | ((unsigned int)hi3 << 16);
                pl.x = (unsigned int)lo0 | ((unsigned int)lo1 << 16);
                pl.y = (unsigned int)lo2 | ((unsigned int)lo3 << 16);
                *(uint2*)(h_hi + idx) = ph;
                *(uint2*)(h_lo + idx) = pl;
            }
        }
    }
}

// ---------------- GINE conv block: u = block(tin_hi+tin_lo); h += gelu(ln(u, nm))
__global__ __launch_bounds__(256) void conv_mfma(
    const unsigned short* __restrict__ tin_hi, const unsigned short* __restrict__ tin_lo,
    unsigned short* __restrict__ h_hi, unsigned short* __restrict__ h_lo,
    const unsigned short* __restrict__ wt1, const float* __restrict__ b1,
    const float* __restrict__ g1, const float* __restrict__ be1,
    const unsigned short* __restrict__ wt2, const float* __restrict__ b2,
    const float* __restrict__ g2, const float* __restrict__ be2,
    const float* __restrict__ nmg, const float* __restrict__ nmb, int rows) {
    __shared__ __align__(16) unsigned short s_A[TILE * ST];
    __shared__ __align__(16) unsigned short s_L[TILE * ST];
    __shared__ float s_vec[8][HD];

    int tid = threadIdx.x;
    int row0 = blockIdx.x * TILE;
    if (tid < HD) {
        s_vec[0][tid] = b1[tid];  s_vec[1][tid] = g1[tid];  s_vec[2][tid] = be1[tid];
        s_vec[3][tid] = b2[tid];  s_vec[4][tid] = g2[tid];  s_vec[5][tid] = be2[tid];
        s_vec[6][tid] = nmg[tid]; s_vec[7][tid] = nmb[tid];
    }
    // stage hi+lo bf16 tin -> LDS (straight 16B copies)
#pragma unroll
    for (int i = 0; i < 4; ++i) {
        int c = tid + i * 256;  // 1024 chunks of 8 bf16
        int r = c >> 4, cc = (c & 15) * 8;
        int gr = min(row0 + r, rows - 1);
        *(uint4*)&s_A[r * ST + cc] = *(const uint4*)(tin_hi + (size_t)gr * HD + cc);
        *(uint4*)&s_L[r * ST + cc] = *(const uint4*)(tin_lo + (size_t)gr * HD + cc);
    }
    __syncthreads();

    int wave = tid >> 6, lane = tid & 63;
    int m = lane & 15, kb = lane >> 4;
    int wrow = wave * 16;
    f32x4 acc[8];
    float u[8][4];

    mm_mfma2(s_A, s_L, wrow, lane, wt1, acc);
    bias_ln_gelu(acc, u, s_vec[0], s_vec[1], s_vec[2], kb);
    __syncthreads();  // all stage-1 LDS reads complete before t1 overwrite
#pragma unroll
    for (int n0 = 0; n0 < 8; ++n0) {
        uint2 p;
        p.x = pk2bf(u[n0][0], u[n0][1]);
        p.y = pk2bf(u[n0][2], u[n0][3]);
        *(uint2*)&s_A[(wrow + m) * ST + n0 * 16 + kb * 4] = p;
    }
    __syncthreads();

    mm_mfma(s_A, wrow, lane, wt2, acc);
    bias_ln_gelu(acc, u, s_vec[3], s_vec[4], s_vec[5], kb);
    // second LN (nm) + GELU, same layout
    {
        float s = 0.f, ss = 0.f;
#pragma unroll
        for (int n0 = 0; n0 < 8; ++n0)
#pragma unroll
            for (int q = 0; q < 4; ++q) { s += u[n0][q]; ss += u[n0][q] * u[n0][q]; }
        s += __shfl_xor(s, 16); ss += __shfl_xor(ss, 16);
        s += __shfl_xor(s, 32); ss += __shfl_xor(ss, 32);
        float mean = s * (1.f / HD);
        float inv = rsqrtf(ss * (1.f / HD) - mean * mean + 1e-5f);
#pragma unroll
        for (int n0 = 0; n0 < 8; ++n0)
#pragma unroll
            for (int q = 0; q < 4; ++q) {
                int c = n0 * 16 + kb * 4 + q;
                u[n0][q] = gelu_f((u[n0][q] - mean) * inv * s_vec[6][c] + s_vec[7][c]);
            }
    }
    int grow = row0 + wrow + m;
    if (grow < rows) {
#pragma unroll
        for (int n0 = 0; n0 < 8; ++n0) {
            size_t idx = (size_t)grow * HD + n0 * 16 + kb * 4;
            uint2 ph = *(const uint2*)(h_hi + idx);
            uint2 pl = *(const uint2*)(h_lo + idx);
            float v0 = h2f_lo(ph.x) + h2f_lo(pl.x) + u[n0][0];
            float v1 = h2f_hi(ph.x) + h2f_hi(pl.x) + u[n0][1];
            float v2 = h2f_lo(ph.y) + h2f_lo(pl.y) + u[n0][2];
            float v3 = h2f_hi(ph.y) + h2f_hi(pl.y) + u[n0][3];
            unsigned short hi0, lo0, hi1, lo1, hi2, lo2, hi3, lo3;
            split_h(v0, hi0, lo0); split_h(v1, hi1, lo1);
            split_h(v2, hi2, lo2); split_h(v3, hi3, lo3);
            ph.x = (unsigned int)hi0 | ((unsigned int)hi1 << 16);
            ph.y = (unsigned int)hi2 | ((unsigned int)hi3 << 16);
            pl.x = (unsigned int)lo0 | ((unsigned int)lo1 << 16);
            pl.y = (unsigned int)lo2 | ((unsigned int)lo3 << 16);
            *(uint2*)(h_hi + idx) = ph;
            *(uint2*)(h_lo + idx) = pl;
        }
    }
}

// ---------------- CSR build (DETERMINISTIC: segments sorted by edge id) ----------------
__global__ void zero_kernel(int* p, int n) {
    int i = blockIdx.x * 256 + threadIdx.x;
    if (i < n) p[i] = 0;
}
__global__ void hist_kernel(const int* __restrict__ dst, int* __restrict__ cnt, int n) {
    for (int i = blockIdx.x * 256 + threadIdx.x; i < n; i += gridDim.x * 256)
        atomicAdd(&cnt[dst[i]], 1);
}
__global__ __launch_bounds__(1024) void scan_block_kernel(
    const int* __restrict__ cnt, int* __restrict__ incl, int* __restrict__ bsum, int n) {
    __shared__ int buf[2][1024];
    int t = threadIdx.x;
    int i = blockIdx.x * 1024 + t;
    int v = (i < n) ? cnt[i] : 0;
    buf[0][t] = v;
    __syncthreads();
    int pin = 0;
    for (int off = 1; off < 1024; off <<= 1) {
        int x = buf[pin][t];
        if (t >= off) x += buf[pin][t - off];
        buf[pin ^ 1][t] = x;
        __syncthreads();
        pin ^= 1;
    }
    if (i < n) incl[i] = buf[pin][t];
    if (t == 1023) bsum[blockIdx.x] = buf[pin][t];
}
__global__ void scan_top_kernel(int* bsum, int nb) {
    int t = threadIdx.x;  // 64 threads
    int v = (t < nb) ? bsum[t] : 0;
    int orig = v;
#pragma unroll
    for (int off = 1; off < 64; off <<= 1) {
        int y = __shfl_up(v, off);
        if (t >= off) v += y;
    }
    if (t < nb) bsum[t] = v - orig;
}
__global__ void add_off_kernel(int* __restrict__ offs, const int* __restrict__ bsum,
                               int* __restrict__ cursor, int n) {
    int i = blockIdx.x * 256 + threadIdx.x;
    if (i == 0) { offs[0] = 0; cursor[0] = 0; }
    if (i < n) {
        int v = offs[i + 1] + bsum[i >> 10];
        offs[i + 1] = v;
        if (i + 1 < n) cursor[i + 1] = v;
    }
}
// scatter: ticket eids into slots (slot order nondeterministic; fixed by sort below)
__global__ void scatter_kernel(const int* __restrict__ dstArr, int* __restrict__ cursor,
                               int* __restrict__ eidslot, int n) {
    for (int i = blockIdx.x * 256 + threadIdx.x; i < n; i += gridDim.x * 256) {
        int d = dstArr[i];
        int p = atomicAdd(&cursor[d], 1);
        eidslot[p] = i;
    }
}
// insertion-sort each node's segment by eid -> canonical (deterministic) order
__global__ void sort_seg_kernel(const int* __restrict__ offs, int* __restrict__ eidslot, int n) {
    int node = blockIdx.x * 256 + threadIdx.x;
    if (node >= n) return;
    int beg = offs[node], end = offs[node + 1];
    for (int p = beg + 1; p < end; ++p) {
        int v = eidslot[p];
        int q = p - 1;
        while (q >= beg && eidslot[q] > v) { eidslot[q + 1] = eidslot[q]; --q; }
        eidslot[q + 1] = v;
    }
}
// finalize: esrc[p] = src[eid[p]] (in place over eidslot), pos[eid[p]] = p
__global__ void finalize_kernel(const int* __restrict__ srcArr, int* __restrict__ eidslot,
                                int* __restrict__ pos, int n) {
    int p = blockIdx.x * 256 + threadIdx.x;
    if (p < n) {
        int t = eidslot[p];
        pos[t] = p;
        eidslot[p] = srcArr[t];  // becomes esrc
    }
}

// ---------------- aggregate: tin = h + sum relu(h[src]+e)
// h gathered via FP16 hi plane (half traffic); self term hi+lo (full precision);
// e FP16 CSR-order. Writes bf16 hi/lo tin pair. Strictly serial accumulation.
__global__ __launch_bounds__(256) void aggregate_kernel(
    const unsigned short* __restrict__ h_hi, const unsigned short* __restrict__ h_lo,
    const unsigned short* __restrict__ e,
    const int* __restrict__ offs, const int* __restrict__ esrc,
    unsigned short* __restrict__ tin_hi, unsigned short* __restrict__ tin_lo, int nnodes) {
    int wave = threadIdx.x >> 6, lane = threadIdx.x & 63;
    int n = blockIdx.x * 4 + wave;
    if (n >= nnodes) return;
    int beg = offs[n], end = offs[n + 1];
    float ax = 0.f, ay = 0.f;
    int i = beg;
    for (; i + 4 <= end; i += 4) {
        int s0 = esrc[i], s1 = esrc[i + 1], s2 = esrc[i + 2], s3 = esrc[i + 3];
        unsigned int g0 = *(const unsigned int*)(h_hi + (size_t)s0 * HD + 2 * lane);
        unsigned int g1 = *(const unsigned int*)(h_hi + (size_t)s1 * HD + 2 * lane);
        unsigned int g2 = *(const unsigned int*)(h_hi + (size_t)s2 * HD + 2 * lane);
        unsigned int g3 = *(const unsigned int*)(h_hi + (size_t)s3 * HD + 2 * lane);
        unsigned int e0 = *(const unsigned int*)(e + (size_t)(i + 0) * HD + 2 * lane);
        unsigned int e1 = *(const unsigned int*)(e + (size_t)(i + 1) * HD + 2 * lane);
        unsigned int e2 = *(const unsigned int*)(e + (size_t)(i + 2) * HD + 2 * lane);
        unsigned int e3 = *(const unsigned int*)(e + (size_t)(i + 3) * HD + 2 * lane);
        ax += fmaxf(h2f_lo(g0) + h2f_lo(e0), 0.f);
        ay += fmaxf(h2f_hi(g0) + h2f_hi(e0), 0.f);
        ax += fmaxf(h2f_lo(g1) + h2f_lo(e1), 0.f);
        ay += fmaxf(h2f_hi(g1) + h2f_hi(e1), 0.f);
        ax += fmaxf(h2f_lo(g2) + h2f_lo(e2), 0.f);
        ay += fmaxf(h2f_hi(g2) + h2f_hi(e2), 0.f);
        ax += fmaxf(h2f_lo(g3) + h2f_lo(e3), 0.f);
        ay += fmaxf(h2f_hi(g3) + h2f_hi(e3), 0.f);
    }
    for (; i < end; ++i) {
        int src = esrc[i];
        unsigned int gh = *(const unsigned int*)(h_hi + (size_t)src * HD + 2 * lane);
        unsigned int ue = *(const unsigned int*)(e + (size_t)i * HD + 2 * lane);
        ax += fmaxf(h2f_lo(gh) + h2f_lo(ue), 0.f);
        ay += fmaxf(h2f_hi(gh) + h2f_hi(ue), 0.f);
    }
    unsigned int shh = *(const unsigned int*)(h_hi + (size_t)n * HD + 2 * lane);
    unsigned int shl = *(const unsigned int*)(h_lo + (size_t)n * HD + 2 * lane);
    float tx = (h2f_lo(shh) + h2f_lo(shl)) + ax;
    float ty = (h2f_hi(shh) + h2f_hi(shl)) + ay;
    unsigned short hx = f2bf(tx), hy = f2bf(ty);
    float lx = tx - bf2f(hx), ly = ty - bf2f(hy);
    *(unsigned int*)(tin_hi + (size_t)n * HD + 2 * lane) =
        (unsigned int)hx | ((unsigned int)hy << 16);
    *(unsigned int*)(tin_lo + (size_t)n * HD + 2 * lane) = pk2bf(lx, ly);
}

// ---------------- heads ----------------
__global__ __launch_bounds__(256) void head_kernel(
    const unsigned short* __restrict__ h_hi, const unsigned short* __restrict__ h_lo,
    const float* __restrict__ dw1,
    const float* __restrict__ db1, const float* __restrict__ dg,
    const float* __restrict__ dbe, const float* __restrict__ dw2,
    const float* __restrict__ db2, const float* __restrict__ sw1,
    const float* __restrict__ sb1, const float* __restrict__ sg,
    const float* __restrict__ sbe, const float* __restrict__ sw2,
    const float* __restrict__ sb2, float* __restrict__ out, int nnodes) {
    __shared__ float s_wd[HD * 64];
    __shared__ float s_ws[HD * 64];
    __shared__ float s_vd[3][64];
    __shared__ float s_vs[3][64];
    __shared__ float s_w2d[64 * 3];
    __shared__ float s_w2s[64];
    __shared__ float s_h[4][HD];
    __shared__ float s_b2[4];

    int tid = threadIdx.x;
    for (int i = tid; i < HD * 64; i += 256) { s_wd[i] = dw1[i]; s_ws[i] = sw1[i]; }
    if (tid < 64) {
        s_vd[0][tid] = db1[tid]; s_vd[1][tid] = dg[tid]; s_vd[2][tid] = dbe[tid];
        s_vs[0][tid] = sb1[tid]; s_vs[1][tid] = sg[tid]; s_vs[2][tid] = sbe[tid];
        s_w2s[tid] = sw2[tid];
    }
    if (tid < 64 * 3) s_w2d[tid] = dw2[tid];
    if (tid == 0) { s_b2[0] = db2[0]; s_b2[1] = db2[1]; s_b2[2] = db2[2]; s_b2[3] = sb2[0]; }
    __syncthreads();

    int wave = tid >> 6, lane = tid & 63;
    float* disp = out;
    float* stress = out + (size_t)nnodes * 3;
    float* hout = out + (size_t)nnodes * 4;

    for (int n = blockIdx.x * 4 + wave; n < nnodes; n += gridDim.x * 4) {
        unsigned int ph = *(const unsigned int*)(h_hi + (size_t)n * HD + lane * 2);
        unsigned int pl = *(const unsigned int*)(h_lo + (size_t)n * HD + lane * 2);
        float hvx = h2f_lo(ph) + h2f_lo(pl);
        float hvy = h2f_hi(ph) + h2f_hi(pl);
        *(float2*)(hout + (size_t)n * HD + lane * 2) = make_float2(hvx, hvy);
        s_h[wave][lane * 2] = hvx;
        s_h[wave][lane * 2 + 1] = hvy;
        float accd = s_vd[0][lane], accs = s_vs[0][lane];
        for (int k = 0; k < HD; ++k) {
            float hx = s_h[wave][k];
            accd = fmaf(hx, s_wd[k * 64 + lane], accd);
            accs = fmaf(hx, s_ws[k * 64 + lane], accs);
        }
        float s = accd, ss = accd * accd;
#pragma unroll
        for (int msk = 1; msk < 64; msk <<= 1) { s += __shfl_xor(s, msk); ss += __shfl_xor(ss, msk); }
        float mean = s * (1.f / 64), inv = rsqrtf(ss * (1.f / 64) - mean * mean + 1e-5f);
        float d = gelu_f((accd - mean) * inv * s_vd[1][lane] + s_vd[2][lane]);
        s = accs; ss = accs * accs;
#pragma unroll
        for (int msk = 1; msk < 64; msk <<= 1) { s += __shfl_xor(s, msk); ss += __shfl_xor(ss, msk); }
        mean = s * (1.f / 64); inv = rsqrtf(ss * (1.f / 64) - mean * mean + 1e-5f);
        float sv = gelu_f((accs - mean) * inv * s_vs[1][lane] + s_vs[2][lane]);
        float p0 = d * s_w2d[lane * 3 + 0];
        float p1 = d * s_w2d[lane * 3 + 1];
        float p2 = d * s_w2d[lane * 3 + 2];
        float ps = sv * s_w2s[lane];
#pragma unroll
        for (int msk = 1; msk < 64; msk <<= 1) {
            p0 += __shfl_xor(p0, msk); p1 += __shfl_xor(p1, msk);
            p2 += __shfl_xor(p2, msk); ps += __shfl_xor(ps, msk);
        }
        if (lane == 0) {
            disp[(size_t)n * 3 + 0] = p0 + s_b2[0];
            disp[(size_t)n * 3 + 1] = p1 + s_b2[1];
            disp[(size_t)n * 3 + 2] = p2 + s_b2[2];
            float xs = ps + s_b2[3];
            stress[n] = fmaxf(xs, 0.f) + log1pf(expf(-fabsf(xs)));
        }
    }
}

extern "C" void kernel_launch(void* const* d_in, const int* in_sizes, int n_in,
                              void* d_out, int out_size, void* d_ws, size_t ws_size,
                              hipStream_t stream) {
    const float* x = (const float*)d_in[0];
    const int* ei = (const int*)d_in[1];
    const float* ea = (const float*)d_in[2];
    const float* ne_w1 = (const float*)d_in[3];
    const float* ne_b1 = (const float*)d_in[4];
    const float* ne_g1 = (const float*)d_in[5];
    const float* ne_be1 = (const float*)d_in[6];
    const float* ne_w2 = (const float*)d_in[7];
    const float* ne_b2 = (const float*)d_in[8];
    const float* ne_g2 = (const float*)d_in[9];
    const float* ne_be2 = (const float*)d_in[10];
    const float* ee_w1 = (const float*)d_in[11];
    const float* ee_b1 = (const float*)d_in[12];
    const float* ee_g1 = (const float*)d_in[13];
    const float* ee_be1 = (const float*)d_in[14];
    const float* ee_w2 = (const float*)d_in[15];
    const float* ee_b2 = (const float*)d_in[16];
    const float* ee_g2 = (const float*)d_in[17];
    const float* ee_be2 = (const float*)d_in[18];
    const float* cv_w1 = (const float*)d_in[19];
    const float* cv_b1 = (const float*)d_in[20];
    const float* cv_g1 = (const float*)d_in[21];
    const float* cv_be1 = (const float*)d_in[22];
    const float* cv_w2 = (const float*)d_in[23];
    const float* cv_b2 = (const float*)d_in[24];
    const float* cv_g2 = (const float*)d_in[25];
    const float* cv_be2 = (const float*)d_in[26];
    const float* nm_g = (const float*)d_in[27];
    const float* nm_b = (const float*)d_in[28];
    const float* dh_w1 = (const float*)d_in[29];
    const float* dh_b1 = (const float*)d_in[30];
    const float* dh_g = (const float*)d_in[31];
    const float* dh_be = (const float*)d_in[32];
    const float* dh_w2 = (const float*)d_in[33];
    const float* dh_b2 = (const float*)d_in[34];
    const float* sh_w1 = (const float*)d_in[35];
    const float* sh_b1 = (const float*)d_in[36];
    const float* sh_g = (const float*)d_in[37];
    const float* sh_be = (const float*)d_in[38];
    const float* sh_w2 = (const float*)d_in[39];
    const float* sh_b2 = (const float*)d_in[40];

    int N = in_sizes[0] / 6;
    int E = in_sizes[1] / 2;

    char* wp = (char*)d_ws;
    auto take = [&](size_t bytes) {
        char* p = wp;
        wp += (bytes + 255) & ~(size_t)255;
        return p;
    };
    unsigned short* e_perm = (unsigned short*)take((size_t)E * HD * 2);   // 204.8 MB (fp16)
    unsigned short* h_hi = (unsigned short*)take((size_t)N * HD * 2);      // 12.8 MB
    unsigned short* h_lo = (unsigned short*)take((size_t)N * HD * 2);      // 12.8 MB
    unsigned short* tin_hi = (unsigned short*)take((size_t)N * HD * 2);    // 12.8 MB
    unsigned short* tin_lo = (unsigned short*)take((size_t)N * HD * 2);    // 12.8 MB
    unsigned short* wbf = (unsigned short*)take((size_t)10 * HD * HD * 2);
    int* cnt = (int*)take((size_t)N * 4);
    int* offs = (int*)take((size_t)(N + 1) * 4);
    int* cursor = (int*)take((size_t)N * 4);
    int* bsum = (int*)take(256);
    int* pos = (int*)take((size_t)E * 4);
    int* esrc = (int*)take((size_t)E * 4);  // holds eids during CSR build, then srcs

    const int* srcArr = ei;
    const int* dstArr = ei + E;

    int nbN = (N + TILE - 1) / TILE;
    int nbE = (E + TILE - 1) / TILE;

    prep_weights<<<10, 256, 0, stream>>>(ne_w2, ee_w2, cv_w1, cv_w2, wbf);
    zero_kernel<<<(N + 255) / 256, 256, 0, stream>>>(cnt, N);
    hist_kernel<<<2048, 256, 0, stream>>>(dstArr, cnt, E);
    int nsb = (N + 1023) / 1024;
    scan_block_kernel<<<nsb, 1024, 0, stream>>>(cnt, offs + 1, bsum, N);
    scan_top_kernel<<<1, 64, 0, stream>>>(bsum, nsb);
    add_off_kernel<<<(N + 255) / 256, 256, 0, stream>>>(offs, bsum, cursor, N);
    scatter_kernel<<<2048, 256, 0, stream>>>(dstArr, cursor, esrc, E);
    sort_seg_kernel<<<(N + 255) / 256, 256, 0, stream>>>(offs, esrc, N);
    finalize_kernel<<<(E + 255) / 256, 256, 0, stream>>>(srcArr, esrc, pos, E);

    encoder_mfma<6, false><<<nbN, 256, 0, stream>>>(
        x, ne_w1, ne_b1, ne_g1, ne_be1, wbf + 0 * HD * HD, ne_b2, ne_g2, ne_be2,
        h_hi, h_lo, nullptr, nullptr, N);
    encoder_mfma<4, true><<<nbE, 256, 0, stream>>>(
        ea, ee_w1, ee_b1, ee_g1, ee_be1, wbf + 1 * HD * HD, ee_b2, ee_g2, ee_be2,
        nullptr, nullptr, e_perm, pos, E);

    for (int l = 0; l < 4; ++l) {
        aggregate_kernel<<<(N + 3) / 4, 256, 0, stream>>>(h_hi, h_lo, e_perm, offs, esrc,
                                                          tin_hi, tin_lo, N);
        conv_mfma<<<nbN, 256, 0, stream>>>(
            tin_hi, tin_lo, h_hi, h_lo, wbf + (size_t)(2 + l) * HD * HD, cv_b1 + l * HD,
            cv_g1 + l * HD, cv_be1 + l * HD, wbf + (size_t)(6 + l) * HD * HD,
            cv_b2 + l * HD, cv_g2 + l * HD, cv_be2 + l * HD,
            nm_g + l * HD, nm_b + l * HD, N);
    }

    head_kernel<<<1024, 256, 0, stream>>>(h_hi, h_lo, dh_w1, dh_b1, dh_g, dh_be,
                                          dh_w2, dh_b2, sh_w1, sh_b1, sh_g, sh_be,
                                          sh_w2, sh_b2, (float*)d_out, N);
}

// Round 15
// 859.259 us; speedup vs baseline: 1.2552x; 1.0004x over previous
//
#include <hip/hip_runtime.h>
#include <hip/hip_bf16.h>
#include <hip/hip_fp16.h>

#define HD 128
#define TILE 64
#define ST 136  // LDS row stride in bf16 (272B; b128/b64 access -> 2-way bank alias, free)

typedef __attribute__((ext_vector_type(8))) short bf16x8;
typedef __attribute__((ext_vector_type(4))) float f32x4;

// fast GELU (A&S 7.1.26, |eps|<=1.5e-7). Safe only with the hi/lo tin pair (R8):
// the single-plane tin->bf16 quantizer amplified 1e-6 perturbations into 0.25
// absmax failures (R3/R4/R6).
__device__ __forceinline__ float gelu_f(float x) {
    float y = fabsf(x) * 0.70710678118654752f;
    float t = __builtin_amdgcn_rcpf(fmaf(0.3275911f, y, 1.0f));
    float p = t * fmaf(t, fmaf(t, fmaf(t, fmaf(t, 1.061405429f, -1.453152027f),
                                       1.421413741f), -0.284496736f), 0.254829592f);
    float E = fmaf(-p, __expf(-y * y), 1.0f);
    return 0.5f * x * (1.0f + copysignf(E, x));
}
__device__ __forceinline__ unsigned short f2bf(float f) {
    unsigned int x = __float_as_uint(f);
    x = x + 0x7fffu + ((x >> 16) & 1u);
    return (unsigned short)(x >> 16);
}
__device__ __forceinline__ unsigned int pk2bf(float lo, float hi) {
    return (unsigned int)f2bf(lo) | ((unsigned int)f2bf(hi) << 16);
}
__device__ __forceinline__ float bf2f(unsigned short u) {
    return __uint_as_float((unsigned int)u << 16);
}
// fp16 helpers (RNE) — storage dtypes only (never feed MFMA)
__device__ __forceinline__ unsigned int pk2h(float lo, float hi) {
    return (unsigned int)__half_as_ushort(__float2half(lo)) |
           ((unsigned int)__half_as_ushort(__float2half(hi)) << 16);
}
__device__ __forceinline__ float h2f_lo(unsigned int u) {
    return __half2float(__ushort_as_half((unsigned short)(u & 0xffffu)));
}
__device__ __forceinline__ float h2f_hi(unsigned int u) {
    return __half2float(__ushort_as_half((unsigned short)(u >> 16)));
}
// split fp32 -> fp16 hi + fp16 residual (combined ~22-bit accuracy)
__device__ __forceinline__ void split_h(float v, unsigned short& hi, unsigned short& lo) {
    __half hh = __float2half(v);
    hi = __half_as_ushort(hh);
    lo = __half_as_ushort(__float2half(v - __half2float(hh)));
}

// OPERAND-SWAPPED MFMA: D = Wt_frag (A-op) x X_frag (B-op).
// wt layout: wt[((n0*4+kk)*64+l)*8+e] = W[kk*32+(l>>4)*8+e][n0*16+(l&15)]
// Result: acc[n0][q] = u[node wrow+(l&15)][feature n0*16+(l>>4)*4+q]
__device__ __forceinline__ void mm_mfma(const unsigned short* sA, int wrow, int lane,
                                        const unsigned short* __restrict__ wt, f32x4 acc[8]) {
    int m = lane & 15, kb = lane >> 4;
    bf16x8 a[4];
#pragma unroll
    for (int kk = 0; kk < 4; ++kk)
        a[kk] = *(const bf16x8*)(sA + (wrow + m) * ST + kk * 32 + kb * 8);
#pragma unroll
    for (int n0 = 0; n0 < 8; ++n0) {
        f32x4 c = {0.f, 0.f, 0.f, 0.f};
#pragma unroll
        for (int kk = 0; kk < 4; ++kk) {
            bf16x8 b = *(const bf16x8*)(wt + ((size_t)((n0 * 4 + kk) * 64 + lane)) * 8);
            c = __builtin_amdgcn_mfma_f32_16x16x32_bf16(b, a[kk], c, 0, 0, 0);
        }
        acc[n0] = c;
    }
}

// two-plane (hi+lo): acc = W^T x (Hi + Lo), chained accumulation
__device__ __forceinline__ void mm_mfma2(const unsigned short* sH, const unsigned short* sL,
                                         int wrow, int lane,
                                         const unsigned short* __restrict__ wt, f32x4 acc[8]) {
    int m = lane & 15, kb = lane >> 4;
    bf16x8 ah[4], al[4];
#pragma unroll
    for (int kk = 0; kk < 4; ++kk) {
        ah[kk] = *(const bf16x8*)(sH + (wrow + m) * ST + kk * 32 + kb * 8);
        al[kk] = *(const bf16x8*)(sL + (wrow + m) * ST + kk * 32 + kb * 8);
    }
#pragma unroll
    for (int n0 = 0; n0 < 8; ++n0) {
        f32x4 c = {0.f, 0.f, 0.f, 0.f};
#pragma unroll
        for (int kk = 0; kk < 4; ++kk) {
            bf16x8 b = *(const bf16x8*)(wt + ((size_t)((n0 * 4 + kk) * 64 + lane)) * 8);
            c = __builtin_amdgcn_mfma_f32_16x16x32_bf16(b, ah[kk], c, 0, 0, 0);
            c = __builtin_amdgcn_mfma_f32_16x16x32_bf16(b, al[kk], c, 0, 0, 0);
        }
        acc[n0] = c;
    }
}

// bias + LN + GELU for the swapped C-layout: lane owns node wrow+m, 32 values
// u[n0][q] = feature n0*16+kb*4+q. Row-reduce = local sum + xor16/xor32.
__device__ __forceinline__ void bias_ln_gelu(f32x4 acc[8], float u[8][4],
                                             const float* bias, const float* g,
                                             const float* be, int kb) {
    float s = 0.f, ss = 0.f;
#pragma unroll
    for (int n0 = 0; n0 < 8; ++n0)
#pragma unroll
        for (int q = 0; q < 4; ++q) {
            float x = acc[n0][q] + bias[n0 * 16 + kb * 4 + q];
            u[n0][q] = x;
            s += x; ss += x * x;
        }
    s += __shfl_xor(s, 16); ss += __shfl_xor(ss, 16);
    s += __shfl_xor(s, 32); ss += __shfl_xor(ss, 32);
    float mean = s * (1.f / HD);
    float inv = rsqrtf(ss * (1.f / HD) - mean * mean + 1e-5f);
#pragma unroll
    for (int n0 = 0; n0 < 8; ++n0)
#pragma unroll
        for (int q = 0; q < 4; ++q) {
            int c = n0 * 16 + kb * 4 + q;
            u[n0][q] = gelu_f((u[n0][q] - mean) * inv * g[c] + be[c]);
        }
}

// ---------------- weight prep: bf16 + MFMA-fragment order (10 matrices 128x128)
__global__ void prep_weights(const float* __restrict__ ne_w2, const float* __restrict__ ee_w2,
                             const float* __restrict__ cv_w1, const float* __restrict__ cv_w2,
                             unsigned short* __restrict__ wbf) {
    int mat = blockIdx.x;
    const float* src = (mat == 0) ? ne_w2
                     : (mat == 1) ? ee_w2
                     : (mat < 6)  ? cv_w1 + (size_t)(mat - 2) * HD * HD
                                  : cv_w2 + (size_t)(mat - 6) * HD * HD;
    unsigned short* dst = wbf + (size_t)mat * HD * HD;
    for (int i = threadIdx.x; i < HD * HD; i += 256) {
        int e = i & 7, lane = (i >> 3) & 63, f = i >> 9;  // f = n0*4+kk
        int m = lane & 15, kb = lane >> 4;
        int n0 = f >> 2, kk = f & 3;
        int k = kk * 32 + kb * 8 + e;
        int c = n0 * 16 + m;
        dst[i] = f2bf(src[(size_t)k * HD + c]);
    }
}

// ---------------- encoder: Linear(IN_DIM->128)+LN+GELU, MFMA Linear(128->128)+LN+GELU
template <int IN_DIM, bool EDGE>
__global__ __launch_bounds__(256) void encoder_mfma(
    const float* __restrict__ in, const float* __restrict__ w1,
    const float* __restrict__ b1, const float* __restrict__ g1,
    const float* __restrict__ be1, const unsigned short* __restrict__ wt2,
    const float* __restrict__ b2, const float* __restrict__ g2,
    const float* __restrict__ be2, unsigned short* __restrict__ h_hi,
    unsigned short* __restrict__ h_lo, unsigned short* __restrict__ e_perm,
    const int* __restrict__ pos, int rows) {
    __shared__ __align__(16) unsigned short s_A[TILE * ST];
    __shared__ float s_vec[6][HD];
    __shared__ int s_pos[TILE];

    int tid = threadIdx.x;
    int row0 = blockIdx.x * TILE;
    if (tid < HD) {
        s_vec[0][tid] = b1[tid]; s_vec[1][tid] = g1[tid]; s_vec[2][tid] = be1[tid];
        s_vec[3][tid] = b2[tid]; s_vec[4][tid] = g2[tid]; s_vec[5][tid] = be2[tid];
    }
    if (EDGE && tid < TILE) {
        int gr = row0 + tid;
        s_pos[tid] = (gr < rows) ? pos[gr] : 0;
    }
    __syncthreads();

    // phase A: thread (tr,tc) owns rows r0..r0+3, cols c0..c0+7; w1 in registers
    int tr = tid >> 4, tc = tid & 15;
    int r0 = tr * 4, c0 = tc * 8;
    float w1r[IN_DIM][8];
#pragma unroll
    for (int k = 0; k < IN_DIM; ++k) {
        float4 pa = *(const float4*)(w1 + (size_t)k * HD + c0);
        float4 pb = *(const float4*)(w1 + (size_t)k * HD + c0 + 4);
        w1r[k][0] = pa.x; w1r[k][1] = pa.y; w1r[k][2] = pa.z; w1r[k][3] = pa.w;
        w1r[k][4] = pb.x; w1r[k][5] = pb.y; w1r[k][6] = pb.z; w1r[k][7] = pb.w;
    }
    float v[4][8];
#pragma unroll
    for (int i = 0; i < 4; ++i)
#pragma unroll
        for (int j = 0; j < 8; ++j) v[i][j] = s_vec[0][c0 + j];
#pragma unroll
    for (int i = 0; i < 4; ++i) {
        int gr = min(row0 + r0 + i, rows - 1);
        float xr[IN_DIM];
        if constexpr (IN_DIM == 4) {
            float4 t4 = *(const float4*)(in + (size_t)gr * 4);
            xr[0] = t4.x; xr[1] = t4.y; xr[2] = t4.z; xr[3] = t4.w;
        } else {
#pragma unroll
            for (int k = 0; k < IN_DIM; ++k) xr[k] = in[(size_t)gr * IN_DIM + k];
        }
#pragma unroll
        for (int k = 0; k < IN_DIM; ++k)
#pragma unroll
            for (int j = 0; j < 8; ++j) v[i][j] = fmaf(xr[k], w1r[k][j], v[i][j]);
    }
    // LN+GELU per row (16-lane tc groups), pack to LDS
#pragma unroll
    for (int i = 0; i < 4; ++i) {
        float s = 0.f, ss = 0.f;
#pragma unroll
        for (int j = 0; j < 8; ++j) { s += v[i][j]; ss += v[i][j] * v[i][j]; }
#pragma unroll
        for (int msk = 1; msk < 16; msk <<= 1) { s += __shfl_xor(s, msk); ss += __shfl_xor(ss, msk); }
        float mean = s * (1.f / HD);
        float inv = rsqrtf(ss * (1.f / HD) - mean * mean + 1e-5f);
#pragma unroll
        for (int j = 0; j < 8; ++j)
            v[i][j] = gelu_f((v[i][j] - mean) * inv * s_vec[1][c0 + j] + s_vec[2][c0 + j]);
        uint4 q4;
        q4.x = pk2bf(v[i][0], v[i][1]); q4.y = pk2bf(v[i][2], v[i][3]);
        q4.z = pk2bf(v[i][4], v[i][5]); q4.w = pk2bf(v[i][6], v[i][7]);
        *(uint4*)&s_A[(r0 + i) * ST + c0] = q4;
    }
    __syncthreads();

    // phase B: swapped MFMA -> lane owns node wrow+m, features n0*16+kb*4+q
    int wave = tid >> 6, lane = tid & 63;
    int m = lane & 15, kb = lane >> 4;
    int wrow = wave * 16;
    f32x4 acc[8];
    mm_mfma(s_A, wrow, lane, wt2, acc);
    float u[8][4];
    bias_ln_gelu(acc, u, s_vec[3], s_vec[4], s_vec[5], kb);

    if (EDGE) {
        __syncthreads();  // all B-frag LDS reads complete before overwrite
        // stage output as FP16 (e_perm storage dtype; never feeds MFMA)
#pragma unroll
        for (int n0 = 0; n0 < 8; ++n0) {
            uint2 p;
            p.x = pk2h(u[n0][0], u[n0][1]);
            p.y = pk2h(u[n0][2], u[n0][3]);
            *(uint2*)&s_A[(wrow + m) * ST + n0 * 16 + kb * 4] = p;
        }
        __syncthreads();
#pragma unroll
        for (int i = 0; i < 4; ++i) {
            int c = tid + i * 256;  // 1024 chunks of 8 fp16
            int r = c >> 4, cc = (c & 15) * 8;
            int gr = row0 + r;
            if (gr < rows) {
                uint4 q4 = *(uint4*)&s_A[r * ST + cc];
                *(uint4*)(e_perm + (size_t)s_pos[r] * HD + cc) = q4;
            }
        }
    } else {
        int grow = row0 + wrow + m;
        if (grow < rows) {
#pragma unroll
            for (int n0 = 0; n0 < 8; ++n0) {
                size_t idx = (size_t)grow * HD + n0 * 16 + kb * 4;
                unsigned short hi0, lo0, hi1, lo1, hi2, lo2, hi3, lo3;
                split_h(u[n0][0], hi0, lo0); split_h(u[n0][1], hi1, lo1);
                split_h(u[n0][2], hi2, lo2); split_h(u[n0][3], hi3, lo3);
                uint2 ph, pl;
                ph.x = (unsigned int)hi0 | ((unsigned int)hi1 << 16);
                ph.y = (unsigned int)hi2 | ((unsigned int)hi3 << 16);
                pl.x = (unsigned int)lo0 | ((unsigned int)lo1 << 16);
                pl.y = (unsigned int)lo2 | ((unsigned int)lo3 << 16);
                *(uint2*)(h_hi + idx) = ph;
                *(uint2*)(h_lo + idx) = pl;
            }
        }
    }
}

// ---------------- GINE conv block: u = block(tin_hi+tin_lo); h += gelu(ln(u, nm))
__global__ __launch_bounds__(256) void conv_mfma(
    const unsigned short* __restrict__ tin_hi, const unsigned short* __restrict__ tin_lo,
    unsigned short* __restrict__ h_hi, unsigned short* __restrict__ h_lo,
    const unsigned short* __restrict__ wt1, const float* __restrict__ b1,
    const float* __restrict__ g1, const float* __restrict__ be1,
    const unsigned short* __restrict__ wt2, const float* __restrict__ b2,
    const float* __restrict__ g2, const float* __restrict__ be2,
    const float* __restrict__ nmg, const float* __restrict__ nmb, int rows) {
    __shared__ __align__(16) unsigned short s_A[TILE * ST];
    __shared__ __align__(16) unsigned short s_L[TILE * ST];
    __shared__ float s_vec[8][HD];

    int tid = threadIdx.x;
    int row0 = blockIdx.x * TILE;
    if (tid < HD) {
        s_vec[0][tid] = b1[tid];  s_vec[1][tid] = g1[tid];  s_vec[2][tid] = be1[tid];
        s_vec[3][tid] = b2[tid];  s_vec[4][tid] = g2[tid];  s_vec[5][tid] = be2[tid];
        s_vec[6][tid] = nmg[tid]; s_vec[7][tid] = nmb[tid];
    }
    // stage hi+lo bf16 tin -> LDS (straight 16B copies)
#pragma unroll
    for (int i = 0; i < 4; ++i) {
        int c = tid + i * 256;  // 1024 chunks of 8 bf16
        int r = c >> 4, cc = (c & 15) * 8;
        int gr = min(row0 + r, rows - 1);
        *(uint4*)&s_A[r * ST + cc] = *(const uint4*)(tin_hi + (size_t)gr * HD + cc);
        *(uint4*)&s_L[r * ST + cc] = *(const uint4*)(tin_lo + (size_t)gr * HD + cc);
    }
    __syncthreads();

    int wave = tid >> 6, lane = tid & 63;
    int m = lane & 15, kb = lane >> 4;
    int wrow = wave * 16;
    f32x4 acc[8];
    float u[8][4];

    mm_mfma2(s_A, s_L, wrow, lane, wt1, acc);
    bias_ln_gelu(acc, u, s_vec[0], s_vec[1], s_vec[2], kb);
    __syncthreads();  // all stage-1 LDS reads complete before t1 overwrite
#pragma unroll
    for (int n0 = 0; n0 < 8; ++n0) {
        uint2 p;
        p.x = pk2bf(u[n0][0], u[n0][1]);
        p.y = pk2bf(u[n0][2], u[n0][3]);
        *(uint2*)&s_A[(wrow + m) * ST + n0 * 16 + kb * 4] = p;
    }
    __syncthreads();

    mm_mfma(s_A, wrow, lane, wt2, acc);
    bias_ln_gelu(acc, u, s_vec[3], s_vec[4], s_vec[5], kb);
    // second LN (nm) + GELU, same layout
    {
        float s = 0.f, ss = 0.f;
#pragma unroll
        for (int n0 = 0; n0 < 8; ++n0)
#pragma unroll
            for (int q = 0; q < 4; ++q) { s += u[n0][q]; ss += u[n0][q] * u[n0][q]; }
        s += __shfl_xor(s, 16); ss += __shfl_xor(ss, 16);
        s += __shfl_xor(s, 32); ss += __shfl_xor(ss, 32);
        float mean = s * (1.f / HD);
        float inv = rsqrtf(ss * (1.f / HD) - mean * mean + 1e-5f);
#pragma unroll
        for (int n0 = 0; n0 < 8; ++n0)
#pragma unroll
            for (int q = 0; q < 4; ++q) {
                int c = n0 * 16 + kb * 4 + q;
                u[n0][q] = gelu_f((u[n0][q] - mean) * inv * s_vec[6][c] + s_vec[7][c]);
            }
    }
    int grow = row0 + wrow + m;
    if (grow < rows) {
#pragma unroll
        for (int n0 = 0; n0 < 8; ++n0) {
            size_t idx = (size_t)grow * HD + n0 * 16 + kb * 4;
            uint2 ph = *(const uint2*)(h_hi + idx);
            uint2 pl = *(const uint2*)(h_lo + idx);
            float v0 = h2f_lo(ph.x) + h2f_lo(pl.x) + u[n0][0];
            float v1 = h2f_hi(ph.x) + h2f_hi(pl.x) + u[n0][1];
            float v2 = h2f_lo(ph.y) + h2f_lo(pl.y) + u[n0][2];
            float v3 = h2f_hi(ph.y) + h2f_hi(pl.y) + u[n0][3];
            unsigned short hi0, lo0, hi1, lo1, hi2, lo2, hi3, lo3;
            split_h(v0, hi0, lo0); split_h(v1, hi1, lo1);
            split_h(v2, hi2, lo2); split_h(v3, hi3, lo3);
            ph.x = (unsigned int)hi0 | ((unsigned int)hi1 << 16);
            ph.y = (unsigned int)hi2 | ((unsigned int)hi3 << 16);
            pl.x = (unsigned int)lo0 | ((unsigned int)lo1 << 16);
            pl.y = (unsigned int)lo2 | ((unsigned int)lo3 << 16);
            *(uint2*)(h_hi + idx) = ph;
            *(uint2*)(h_lo + idx) = pl;
        }
    }
}

// ---------------- CSR build (DETERMINISTIC: segments sorted by edge id) ----------------
__global__ void zero_kernel(int* p, int n) {
    int i = blockIdx.x * 256 + threadIdx.x;
    if (i < n) p[i] = 0;
}
__global__ void hist_kernel(const int* __restrict__ dst, int* __restrict__ cnt, int n) {
    for (int i = blockIdx.x * 256 + threadIdx.x; i < n; i += gridDim.x * 256)
        atomicAdd(&cnt[dst[i]], 1);
}
__global__ __launch_bounds__(1024) void scan_block_kernel(
    const int* __restrict__ cnt, int* __restrict__ incl, int* __restrict__ bsum, int n) {
    __shared__ int buf[2][1024];
    int t = threadIdx.x;
    int i = blockIdx.x * 1024 + t;
    int v = (i < n) ? cnt[i] : 0;
    buf[0][t] = v;
    __syncthreads();
    int pin = 0;
    for (int off = 1; off < 1024; off <<= 1) {
        int x = buf[pin][t];
        if (t >= off) x += buf[pin][t - off];
        buf[pin ^ 1][t] = x;
        __syncthreads();
        pin ^= 1;
    }
    if (i < n) incl[i] = buf[pin][t];
    if (t == 1023) bsum[blockIdx.x] = buf[pin][t];
}
__global__ void scan_top_kernel(int* bsum, int nb) {
    int t = threadIdx.x;  // 64 threads
    int v = (t < nb) ? bsum[t] : 0;
    int orig = v;
#pragma unroll
    for (int off = 1; off < 64; off <<= 1) {
        int y = __shfl_up(v, off);
        if (t >= off) v += y;
    }
    if (t < nb) bsum[t] = v - orig;
}
__global__ void add_off_kernel(int* __restrict__ offs, const int* __restrict__ bsum,
                               int* __restrict__ cursor, int n) {
    int i = blockIdx.x * 256 + threadIdx.x;
    if (i == 0) { offs[0] = 0; cursor[0] = 0; }
    if (i < n) {
        int v = offs[i + 1] + bsum[i >> 10];
        offs[i + 1] = v;
        if (i + 1 < n) cursor[i + 1] = v;
    }
}
// scatter: ticket eids into slots (slot order nondeterministic; fixed by sort below)
__global__ void scatter_kernel(const int* __restrict__ dstArr, int* __restrict__ cursor,
                               int* __restrict__ eidslot, int n) {
    for (int i = blockIdx.x * 256 + threadIdx.x; i < n; i += gridDim.x * 256) {
        int d = dstArr[i];
        int p = atomicAdd(&cursor[d], 1);
        eidslot[p] = i;
    }
}
// insertion-sort each node's segment by eid -> canonical (deterministic) order
__global__ void sort_seg_kernel(const int* __restrict__ offs, int* __restrict__ eidslot, int n) {
    int node = blockIdx.x * 256 + threadIdx.x;
    if (node >= n) return;
    int beg = offs[node], end = offs[node + 1];
    for (int p = beg + 1; p < end; ++p) {
        int v = eidslot[p];
        int q = p - 1;
        while (q >= beg && eidslot[q] > v) { eidslot[q + 1] = eidslot[q]; --q; }
        eidslot[q + 1] = v;
    }
}
// finalize: esrc[p] = src[eid[p]] (in place over eidslot), pos[eid[p]] = p
__global__ void finalize_kernel(const int* __restrict__ srcArr, int* __restrict__ eidslot,
                                int* __restrict__ pos, int n) {
    int p = blockIdx.x * 256 + threadIdx.x;
    if (p < n) {
        int t = eidslot[p];
        pos[t] = p;
        eidslot[p] = srcArr[t];  // becomes esrc
    }
}

// ---------------- aggregate: tin = h + sum relu(h[src]+e)
// h gathered via FP16 hi plane; self term hi+lo; e FP16 CSR-order.
// R15: unroll 8 -> 4 -> 1 cascade, batched loads, STRICTLY SERIAL accumulation
// (fp order bit-identical to R14; only memory ops reorder -> 2x MLP).
__global__ __launch_bounds__(256) void aggregate_kernel(
    const unsigned short* __restrict__ h_hi, const unsigned short* __restrict__ h_lo,
    const unsigned short* __restrict__ e,
    const int* __restrict__ offs, const int* __restrict__ esrc,
    unsigned short* __restrict__ tin_hi, unsigned short* __restrict__ tin_lo, int nnodes) {
    int wave = threadIdx.x >> 6, lane = threadIdx.x & 63;
    int n = blockIdx.x * 4 + wave;
    if (n >= nnodes) return;
    int beg = offs[n], end = offs[n + 1];
    float ax = 0.f, ay = 0.f;
    int i = beg;
    for (; i + 8 <= end; i += 8) {
        int s0 = esrc[i], s1 = esrc[i + 1], s2 = esrc[i + 2], s3 = esrc[i + 3];
        int s4 = esrc[i + 4], s5 = esrc[i + 5], s6 = esrc[i + 6], s7 = esrc[i + 7];
        unsigned int g0 = *(const unsigned int*)(h_hi + (size_t)s0 * HD + 2 * lane);
        unsigned int g1 = *(const unsigned int*)(h_hi + (size_t)s1 * HD + 2 * lane);
        unsigned int g2 = *(const unsigned int*)(h_hi + (size_t)s2 * HD + 2 * lane);
        unsigned int g3 = *(const unsigned int*)(h_hi + (size_t)s3 * HD + 2 * lane);
        unsigned int g4 = *(const unsigned int*)(h_hi + (size_t)s4 * HD + 2 * lane);
        unsigned int g5 = *(const unsigned int*)(h_hi + (size_t)s5 * HD + 2 * lane);
        unsigned int g6 = *(const unsigned int*)(h_hi + (size_t)s6 * HD + 2 * lane);
        unsigned int g7 = *(const unsigned int*)(h_hi + (size_t)s7 * HD + 2 * lane);
        unsigned int e0 = *(const unsigned int*)(e + (size_t)(i + 0) * HD + 2 * lane);
        unsigned int e1 = *(const unsigned int*)(e + (size_t)(i + 1) * HD + 2 * lane);
        unsigned int e2 = *(const unsigned int*)(e + (size_t)(i + 2) * HD + 2 * lane);
        unsigned int e3 = *(const unsigned int*)(e + (size_t)(i + 3) * HD + 2 * lane);
        unsigned int e4 = *(const unsigned int*)(e + (size_t)(i + 4) * HD + 2 * lane);
        unsigned int e5 = *(const unsigned int*)(e + (size_t)(i + 5) * HD + 2 * lane);
        unsigned int e6 = *(const unsigned int*)(e + (size_t)(i + 6) * HD + 2 * lane);
        unsigned int e7 = *(const unsigned int*)(e + (size_t)(i + 7) * HD + 2 * lane);
        ax += fmaxf(h2f_lo(g0) + h2f_lo(e0), 0.f);
        ay += fmaxf(h2f_hi(g0) + h2f_hi(e0), 0.f);
        ax += fmaxf(h2f_lo(g1) + h2f_lo(e1), 0.f);
        ay += fmaxf(h2f_hi(g1) + h2f_hi(e1), 0.f);
        ax += fmaxf(h2f_lo(g2) + h2f_lo(e2), 0.f);
        ay += fmaxf(h2f_hi(g2) + h2f_hi(e2), 0.f);
        ax += fmaxf(h2f_lo(g3) + h2f_lo(e3), 0.f);
        ay += fmaxf(h2f_hi(g3) + h2f_hi(e3), 0.f);
        ax += fmaxf(h2f_lo(g4) + h2f_lo(e4), 0.f);
        ay += fmaxf(h2f_hi(g4) + h2f_hi(e4), 0.f);
        ax += fmaxf(h2f_lo(g5) + h2f_lo(e5), 0.f);
        ay += fmaxf(h2f_hi(g5) + h2f_hi(e5), 0.f);
        ax += fmaxf(h2f_lo(g6) + h2f_lo(e6), 0.f);
        ay += fmaxf(h2f_hi(g6) + h2f_hi(e6), 0.f);
        ax += fmaxf(h2f_lo(g7) + h2f_lo(e7), 0.f);
        ay += fmaxf(h2f_hi(g7) + h2f_hi(e7), 0.f);
    }
    for (; i + 4 <= end; i += 4) {
        int s0 = esrc[i], s1 = esrc[i + 1], s2 = esrc[i + 2], s3 = esrc[i + 3];
        unsigned int g0 = *(const unsigned int*)(h_hi + (size_t)s0 * HD + 2 * lane);
        unsigned int g1 = *(const unsigned int*)(h_hi + (size_t)s1 * HD + 2 * lane);
        unsigned int g2 = *(const unsigned int*)(h_hi + (size_t)s2 * HD + 2 * lane);
        unsigned int g3 = *(const unsigned int*)(h_hi + (size_t)s3 * HD + 2 * lane);
        unsigned int e0 = *(const unsigned int*)(e + (size_t)(i + 0) * HD + 2 * lane);
        unsigned int e1 = *(const unsigned int*)(e + (size_t)(i + 1) * HD + 2 * lane);
        unsigned int e2 = *(const unsigned int*)(e + (size_t)(i + 2) * HD + 2 * lane);
        unsigned int e3 = *(const unsigned int*)(e + (size_t)(i + 3) * HD + 2 * lane);
        ax += fmaxf(h2f_lo(g0) + h2f_lo(e0), 0.f);
        ay += fmaxf(h2f_hi(g0) + h2f_hi(e0), 0.f);
        ax += fmaxf(h2f_lo(g1) + h2f_lo(e1), 0.f);
        ay += fmaxf(h2f_hi(g1) + h2f_hi(e1), 0.f);
        ax += fmaxf(h2f_lo(g2) + h2f_lo(e2), 0.f);
        ay += fmaxf(h2f_hi(g2) + h2f_hi(e2), 0.f);
        ax += fmaxf(h2f_lo(g3) + h2f_lo(e3), 0.f);
        ay += fmaxf(h2f_hi(g3) + h2f_hi(e3), 0.f);
    }
    for (; i < end; ++i) {
        int src = esrc[i];
        unsigned int gh = *(const unsigned int*)(h_hi + (size_t)src * HD + 2 * lane);
        unsigned int ue = *(const unsigned int*)(e + (size_t)i * HD + 2 * lane);
        ax += fmaxf(h2f_lo(gh) + h2f_lo(ue), 0.f);
        ay += fmaxf(h2f_hi(gh) + h2f_hi(ue), 0.f);
    }
    unsigned int shh = *(const unsigned int*)(h_hi + (size_t)n * HD + 2 * lane);
    unsigned int shl = *(const unsigned int*)(h_lo + (size_t)n * HD + 2 * lane);
    float tx = (h2f_lo(shh) + h2f_lo(shl)) + ax;
    float ty = (h2f_hi(shh) + h2f_hi(shl)) + ay;
    unsigned short hx = f2bf(tx), hy = f2bf(ty);
    float lx = tx - bf2f(hx), ly = ty - bf2f(hy);
    *(unsigned int*)(tin_hi + (size_t)n * HD + 2 * lane) =
        (unsigned int)hx | ((unsigned int)hy << 16);
    *(unsigned int*)(tin_lo + (size_t)n * HD + 2 * lane) = pk2bf(lx, ly);
}

// ---------------- heads ----------------
__global__ __launch_bounds__(256) void head_kernel(
    const unsigned short* __restrict__ h_hi, const unsigned short* __restrict__ h_lo,
    const float* __restrict__ dw1,
    const float* __restrict__ db1, const float* __restrict__ dg,
    const float* __restrict__ dbe, const float* __restrict__ dw2,
    const float* __restrict__ db2, const float* __restrict__ sw1,
    const float* __restrict__ sb1, const float* __restrict__ sg,
    const float* __restrict__ sbe, const float* __restrict__ sw2,
    const float* __restrict__ sb2, float* __restrict__ out, int nnodes) {
    __shared__ float s_wd[HD * 64];
    __shared__ float s_ws[HD * 64];
    __shared__ float s_vd[3][64];
    __shared__ float s_vs[3][64];
    __shared__ float s_w2d[64 * 3];
    __shared__ float s_w2s[64];
    __shared__ float s_h[4][HD];
    __shared__ float s_b2[4];

    int tid = threadIdx.x;
    for (int i = tid; i < HD * 64; i += 256) { s_wd[i] = dw1[i]; s_ws[i] = sw1[i]; }
    if (tid < 64) {
        s_vd[0][tid] = db1[tid]; s_vd[1][tid] = dg[tid]; s_vd[2][tid] = dbe[tid];
        s_vs[0][tid] = sb1[tid]; s_vs[1][tid] = sg[tid]; s_vs[2][tid] = sbe[tid];
        s_w2s[tid] = sw2[tid];
    }
    if (tid < 64 * 3) s_w2d[tid] = dw2[tid];
    if (tid == 0) { s_b2[0] = db2[0]; s_b2[1] = db2[1]; s_b2[2] = db2[2]; s_b2[3] = sb2[0]; }
    __syncthreads();

    int wave = tid >> 6, lane = tid & 63;
    float* disp = out;
    float* stress = out + (size_t)nnodes * 3;
    float* hout = out + (size_t)nnodes * 4;

    for (int n = blockIdx.x * 4 + wave; n < nnodes; n += gridDim.x * 4) {
        unsigned int ph = *(const unsigned int*)(h_hi + (size_t)n * HD + lane * 2);
        unsigned int pl = *(const unsigned int*)(h_lo + (size_t)n * HD + lane * 2);
        float hvx = h2f_lo(ph) + h2f_lo(pl);
        float hvy = h2f_hi(ph) + h2f_hi(pl);
        *(float2*)(hout + (size_t)n * HD + lane * 2) = make_float2(hvx, hvy);
        s_h[wave][lane * 2] = hvx;
        s_h[wave][lane * 2 + 1] = hvy;
        float accd = s_vd[0][lane], accs = s_vs[0][lane];
        for (int k = 0; k < HD; ++k) {
            float hx = s_h[wave][k];
            accd = fmaf(hx, s_wd[k * 64 + lane], accd);
            accs = fmaf(hx, s_ws[k * 64 + lane], accs);
        }
        float s = accd, ss = accd * accd;
#pragma unroll
        for (int msk = 1; msk < 64; msk <<= 1) { s += __shfl_xor(s, msk); ss += __shfl_xor(ss, msk); }
        float mean = s * (1.f / 64), inv = rsqrtf(ss * (1.f / 64) - mean * mean + 1e-5f);
        float d = gelu_f((accd - mean) * inv * s_vd[1][lane] + s_vd[2][lane]);
        s = accs; ss = accs * accs;
#pragma unroll
        for (int msk = 1; msk < 64; msk <<= 1) { s += __shfl_xor(s, msk); ss += __shfl_xor(ss, msk); }
        mean = s * (1.f / 64); inv = rsqrtf(ss * (1.f / 64) - mean * mean + 1e-5f);
        float sv = gelu_f((accs - mean) * inv * s_vs[1][lane] + s_vs[2][lane]);
        float p0 = d * s_w2d[lane * 3 + 0];
        float p1 = d * s_w2d[lane * 3 + 1];
        float p2 = d * s_w2d[lane * 3 + 2];
        float ps = sv * s_w2s[lane];
#pragma unroll
        for (int msk = 1; msk < 64; msk <<= 1) {
            p0 += __shfl_xor(p0, msk); p1 += __shfl_xor(p1, msk);
            p2 += __shfl_xor(p2, msk); ps += __shfl_xor(ps, msk);
        }
        if (lane == 0) {
            disp[(size_t)n * 3 + 0] = p0 + s_b2[0];
            disp[(size_t)n * 3 + 1] = p1 + s_b2[1];
            disp[(size_t)n * 3 + 2] = p2 + s_b2[2];
            float xs = ps + s_b2[3];
            stress[n] = fmaxf(xs, 0.f) + log1pf(expf(-fabsf(xs)));
        }
    }
}

extern "C" void kernel_launch(void* const* d_in, const int* in_sizes, int n_in,
                              void* d_out, int out_size, void* d_ws, size_t ws_size,
                              hipStream_t stream) {
    const float* x = (const float*)d_in[0];
    const int* ei = (const int*)d_in[1];
    const float* ea = (const float*)d_in[2];
    const float* ne_w1 = (const float*)d_in[3];
    const float* ne_b1 = (const float*)d_in[4];
    const float* ne_g1 = (const float*)d_in[5];
    const float* ne_be1 = (const float*)d_in[6];
    const float* ne_w2 = (const float*)d_in[7];
    const float* ne_b2 = (const float*)d_in[8];
    const float* ne_g2 = (const float*)d_in[9];
    const float* ne_be2 = (const float*)d_in[10];
    const float* ee_w1 = (const float*)d_in[11];
    const float* ee_b1 = (const float*)d_in[12];
    const float* ee_g1 = (const float*)d_in[13];
    const float* ee_be1 = (const float*)d_in[14];
    const float* ee_w2 = (const float*)d_in[15];
    const float* ee_b2 = (const float*)d_in[16];
    const float* ee_g2 = (const float*)d_in[17];
    const float* ee_be2 = (const float*)d_in[18];
    const float* cv_w1 = (const float*)d_in[19];
    const float* cv_b1 = (const float*)d_in[20];
    const float* cv_g1 = (const float*)d_in[21];
    const float* cv_be1 = (const float*)d_in[22];
    const float* cv_w2 = (const float*)d_in[23];
    const float* cv_b2 = (const float*)d_in[24];
    const float* cv_g2 = (const float*)d_in[25];
    const float* cv_be2 = (const float*)d_in[26];
    const float* nm_g = (const float*)d_in[27];
    const float* nm_b = (const float*)d_in[28];
    const float* dh_w1 = (const float*)d_in[29];
    const float* dh_b1 = (const float*)d_in[30];
    const float* dh_g = (const float*)d_in[31];
    const float* dh_be = (const float*)d_in[32];
    const float* dh_w2 = (const float*)d_in[33];
    const float* dh_b2 = (const float*)d_in[34];
    const float* sh_w1 = (const float*)d_in[35];
    const float* sh_b1 = (const float*)d_in[36];
    const float* sh_g = (const float*)d_in[37];
    const float* sh_be = (const float*)d_in[38];
    const float* sh_w2 = (const float*)d_in[39];
    const float* sh_b2 = (const float*)d_in[40];

    int N = in_sizes[0] / 6;
    int E = in_sizes[1] / 2;

    char* wp = (char*)d_ws;
    auto take = [&](size_t bytes) {
        char* p = wp;
        wp += (bytes + 255) & ~(size_t)255;
        return p;
    };
    unsigned short* e_perm = (unsigned short*)take((size_t)E * HD * 2);   // 204.8 MB (fp16)
    unsigned short* h_hi = (unsigned short*)take((size_t)N * HD * 2);      // 12.8 MB
    unsigned short* h_lo = (unsigned short*)take((size_t)N * HD * 2);      // 12.8 MB
    unsigned short* tin_hi = (unsigned short*)take((size_t)N * HD * 2);    // 12.8 MB
    unsigned short* tin_lo = (unsigned short*)take((size_t)N * HD * 2);    // 12.8 MB
    unsigned short* wbf = (unsigned short*)take((size_t)10 * HD * HD * 2);
    int* cnt = (int*)take((size_t)N * 4);
    int* offs = (int*)take((size_t)(N + 1) * 4);
    int* cursor = (int*)take((size_t)N * 4);
    int* bsum = (int*)take(256);
    int* pos = (int*)take((size_t)E * 4);
    int* esrc = (int*)take((size_t)E * 4);  // holds eids during CSR build, then srcs

    const int* srcArr = ei;
    const int* dstArr = ei + E;

    int nbN = (N + TILE - 1) / TILE;
    int nbE = (E + TILE - 1) / TILE;

    prep_weights<<<10, 256, 0, stream>>>(ne_w2, ee_w2, cv_w1, cv_w2, wbf);
    zero_kernel<<<(N + 255) / 256, 256, 0, stream>>>(cnt, N);
    hist_kernel<<<2048, 256, 0, stream>>>(dstArr, cnt, E);
    int nsb = (N + 1023) / 1024;
    scan_block_kernel<<<nsb, 1024, 0, stream>>>(cnt, offs + 1, bsum, N);
    scan_top_kernel<<<1, 64, 0, stream>>>(bsum, nsb);
    add_off_kernel<<<(N + 255) / 256, 256, 0, stream>>>(offs, bsum, cursor, N);
    scatter_kernel<<<2048, 256, 0, stream>>>(dstArr, cursor, esrc, E);
    sort_seg_kernel<<<(N + 255) / 256, 256, 0, stream>>>(offs, esrc, N);
    finalize_kernel<<<(E + 255) / 256, 256, 0, stream>>>(srcArr, esrc, pos, E);

    encoder_mfma<6, false><<<nbN, 256, 0, stream>>>(
        x, ne_w1, ne_b1, ne_g1, ne_be1, wbf + 0 * HD * HD, ne_b2, ne_g2, ne_be2,
        h_hi, h_lo, nullptr, nullptr, N);
    encoder_mfma<4, true><<<nbE, 256, 0, stream>>>(
        ea, ee_w1, ee_b1, ee_g1, ee_be1, wbf + 1 * HD * HD, ee_b2, ee_g2, ee_be2,
        nullptr, nullptr, e_perm, pos, E);

    for (int l = 0; l < 4; ++l) {
        aggregate_kernel<<<(N + 3) / 4, 256, 0, stream>>>(h_hi, h_lo, e_perm, offs, esrc,
                                                          tin_hi, tin_lo, N);
        conv_mfma<<<nbN, 256, 0, stream>>>(
            tin_hi, tin_lo, h_hi, h_lo, wbf + (size_t)(2 + l) * HD * HD, cv_b1 + l * HD,
            cv_g1 + l * HD, cv_be1 + l * HD, wbf + (size_t)(6 + l) * HD * HD,
            cv_b2 + l * HD, cv_g2 + l * HD, cv_be2 + l * HD,
            nm_g + l * HD, nm_b + l * HD, N);
    }

    head_kernel<<<1024, 256, 0, stream>>>(h_hi, h_lo, dh_w1, dh_b1, dh_g, dh_be,
                                          dh_w2, dh_b2, sh_w1, sh_b1, sh_g, sh_be,
                                          sh_w2, sh_b2, (float*)d_out, N);
}